// Round 1
// baseline (477.036 us; speedup 1.0000x reference)
//
#include <hip/hip_runtime.h>
#include <math.h>

#define N_NODES 50000
#define N_EDGES 800000
#define IN_DIM 256
#define HID 64

// ---------------- degree / dinv ----------------
__global__ void k_deg(const int* __restrict__ dst, float* __restrict__ deg) {
  int e = blockIdx.x * 256 + threadIdx.x;
  if (e < N_EDGES) atomicAdd(&deg[dst[e]], 1.0f);
}

__global__ void k_dinv(float* deg) {
  int v = blockIdx.x * 256 + threadIdx.x;
  if (v < N_NODES) deg[v] = 1.0f / sqrtf(deg[v] + 1.0f);  // +1 self-loop
}

// ---------------- GEMM: out[r][c] = dinv[r] * sum_k X[r][k] * W[k][c], C=64 ----------------
// BM=64, BN=64, BK=16; 256 threads; 4x4 outputs per thread.
template <int K>
__global__ void k_gemm_scale(const float* __restrict__ X, const float* __restrict__ W,
                             const float* __restrict__ dinv, float* __restrict__ out) {
  __shared__ float aT[16][68];   // [k][row], padded
  __shared__ float bS[16][64];   // [k][col]
  const int t = threadIdx.x;
  const int row0 = blockIdx.x * 64;
  const int ty = t >> 4, tx = t & 15;

  float acc[4][4] = {};

  for (int k0 = 0; k0 < K; k0 += 16) {
    // stage X tile (64 rows x 16 k) as transposed
    {
      int r = t >> 2, c = t & 3;
      int row = row0 + r;
      int rr = row < N_NODES ? row : N_NODES - 1;  // clamp (guarded at store)
      const float4 v = *reinterpret_cast<const float4*>(&X[(size_t)rr * K + k0 + c * 4]);
      aT[c * 4 + 0][r] = v.x;
      aT[c * 4 + 1][r] = v.y;
      aT[c * 4 + 2][r] = v.z;
      aT[c * 4 + 3][r] = v.w;
    }
    // stage W tile (16 k x 64 cols)
    {
      int kr = t >> 4, c = (t & 15) * 4;
      *reinterpret_cast<float4*>(&bS[kr][c]) =
          *reinterpret_cast<const float4*>(&W[(size_t)(k0 + kr) * 64 + c]);
    }
    __syncthreads();
#pragma unroll
    for (int k = 0; k < 16; ++k) {
      float4 a = *reinterpret_cast<const float4*>(&aT[k][ty * 4]);
      float4 b = *reinterpret_cast<const float4*>(&bS[k][tx * 4]);
      float av[4] = {a.x, a.y, a.z, a.w};
      float bv[4] = {b.x, b.y, b.z, b.w};
#pragma unroll
      for (int i = 0; i < 4; ++i)
#pragma unroll
        for (int j = 0; j < 4; ++j) acc[i][j] += av[i] * bv[j];
    }
    __syncthreads();
  }

  // epilogue: scale by dinv[row], store
#pragma unroll
  for (int i = 0; i < 4; ++i) {
    int row = row0 + ty * 4 + i;
    if (row < N_NODES) {
      float s = dinv[row];
      float4 o;
      o.x = acc[i][0] * s; o.y = acc[i][1] * s; o.z = acc[i][2] * s; o.w = acc[i][3] * s;
      *reinterpret_cast<float4*>(&out[(size_t)row * 64 + tx * 4]) = o;
    }
  }
}

// ---------------- edge scatter: agg[d][lane] += h[s][lane] ----------------
__global__ void k_scatter(const int* __restrict__ src, const int* __restrict__ dst,
                          const float* __restrict__ h, float* __restrict__ agg) {
  int e = blockIdx.x * 4 + (threadIdx.x >> 6);
  int lane = threadIdx.x & 63;
  if (e < N_EDGES) {
    int s = src[e], d = dst[e];
    atomicAdd(&agg[(size_t)d * 64 + lane], h[(size_t)s * 64 + lane]);
  }
}

// ---------------- post: h = relu(dinv[v]*(agg + hs) + bias), in-place into agg ----------------
__global__ void k_post(float* agg, const float* __restrict__ hs,
                       const float* __restrict__ dinv, const float* __restrict__ bias) {
  int idx = blockIdx.x * 256 + threadIdx.x;
  if (idx < N_NODES * HID) {
    int v = idx >> 6, i = idx & 63;
    float val = dinv[v] * (agg[idx] + hs[idx]) + bias[i];
    agg[idx] = fmaxf(val, 0.0f);
  }
}

// ---------------- final: out[v] = sigmoid( relu(dinv*(agg2+h2s)+b2) . Wc + bc ) ----------------
__global__ void k_final(const float* __restrict__ agg2, const float* __restrict__ h2s,
                        const float* __restrict__ dinv, const float* __restrict__ b2,
                        const float* __restrict__ Wc, const float* __restrict__ bc,
                        float* __restrict__ out) {
  int v = blockIdx.x * 4 + (threadIdx.x >> 6);
  int lane = threadIdx.x & 63;
  if (v < N_NODES) {
    int idx = v * 64 + lane;
    float h = fmaxf(dinv[v] * (agg2[idx] + h2s[idx]) + b2[lane], 0.0f);
    float p = h * Wc[lane];
#pragma unroll
    for (int off = 32; off; off >>= 1) p += __shfl_down(p, off);
    if (lane == 0) out[v] = 1.0f / (1.0f + expf(-(p + bc[0])));
  }
}

extern "C" void kernel_launch(void* const* d_in, const int* in_sizes, int n_in,
                              void* d_out, int out_size, void* d_ws, size_t ws_size,
                              hipStream_t stream) {
  const float* x  = (const float*)d_in[0];
  const int*   ei = (const int*)d_in[1];
  const float* W1 = (const float*)d_in[2];
  const float* b1 = (const float*)d_in[3];
  const float* W2 = (const float*)d_in[4];
  const float* b2 = (const float*)d_in[5];
  const float* Wc = (const float*)d_in[6];
  const float* bc = (const float*)d_in[7];
  float* out = (float*)d_out;

  float* ws = (float*)d_ws;
  float* dinv = ws;                       // 50176 floats
  float* A = ws + 50176;                  // N_NODES*64
  float* B = A + (size_t)N_NODES * 64;    // N_NODES*64

  const int* src = ei;
  const int* dst = ei + N_EDGES;

  hipMemsetAsync(dinv, 0, N_NODES * sizeof(float), stream);
  k_deg<<<(N_EDGES + 255) / 256, 256, 0, stream>>>(dst, dinv);
  k_dinv<<<(N_NODES + 255) / 256, 256, 0, stream>>>(dinv);

  // layer 1
  k_gemm_scale<IN_DIM><<<(N_NODES + 63) / 64, 256, 0, stream>>>(x, W1, dinv, A);  // A = h1s
  hipMemsetAsync(B, 0, (size_t)N_NODES * 64 * sizeof(float), stream);
  k_scatter<<<(N_EDGES + 3) / 4, 256, 0, stream>>>(src, dst, A, B);               // B = agg1
  k_post<<<(N_NODES * 64 + 255) / 256, 256, 0, stream>>>(B, A, dinv, b1);         // B = h1

  // layer 2
  k_gemm_scale<HID><<<(N_NODES + 63) / 64, 256, 0, stream>>>(B, W2, dinv, A);     // A = h2s
  hipMemsetAsync(B, 0, (size_t)N_NODES * 64 * sizeof(float), stream);
  k_scatter<<<(N_EDGES + 3) / 4, 256, 0, stream>>>(src, dst, A, B);               // B = agg2

  // classifier
  k_final<<<(N_NODES + 3) / 4, 256, 0, stream>>>(B, A, dinv, b2, Wc, bc, out);
}

// Round 2
// 303.934 us; speedup vs baseline: 1.5695x; 1.5695x over previous
//
#include <hip/hip_runtime.h>
#include <math.h>

#define N_NODES 50000
#define N_EDGES 800000
#define IN_DIM 256
#define HID 64

// ---------------- CSR build ----------------
__global__ void k_hist(const int* __restrict__ dst, int* __restrict__ cnt) {
  int e = blockIdx.x * 256 + threadIdx.x;
  if (e < N_EDGES) atomicAdd(&cnt[dst[e]], 1);
}

// single block, 1024 threads, chunk of 49 nodes each: exclusive scan -> rowptr
__global__ void k_scan(const int* __restrict__ cnt, int* __restrict__ rowptr) {
  __shared__ int part[1024];
  const int t = threadIdx.x;
  const int base = t * 49;
  int sum = 0;
  for (int i = 0; i < 49; ++i) {
    int idx = base + i;
    if (idx < N_NODES) sum += cnt[idx];
  }
  part[t] = sum;
  __syncthreads();
  // Hillis-Steele inclusive scan over 1024 partials
  for (int d = 1; d < 1024; d <<= 1) {
    int v = part[t];
    int add = (t >= d) ? part[t - d] : 0;
    __syncthreads();
    part[t] = v + add;
    __syncthreads();
  }
  int run = (t == 0) ? 0 : part[t - 1];
  for (int i = 0; i < 49; ++i) {
    int idx = base + i;
    if (idx < N_NODES) {
      rowptr[idx] = run;
      run += cnt[idx];
    }
  }
  if (t == 1023) rowptr[N_NODES] = N_EDGES;
}

__global__ void k_dinv(const int* __restrict__ cnt, float* __restrict__ dinv) {
  int v = blockIdx.x * 256 + threadIdx.x;
  if (v < N_NODES) dinv[v] = 1.0f / sqrtf((float)(cnt[v] + 1));  // +1 self-loop
}

__global__ void k_fill(const int* __restrict__ src, const int* __restrict__ dst,
                       const int* __restrict__ rowptr, int* __restrict__ cursor,
                       int* __restrict__ col) {
  int e = blockIdx.x * 256 + threadIdx.x;
  if (e < N_EDGES) {
    int d = dst[e];
    int pos = atomicAdd(&cursor[d], 1);
    col[rowptr[d] + pos] = src[e];
  }
}

// ---------------- GEMM: out[r][c] = dinv[r] * sum_k X[r][k] * W[k][c], C=64 ----------------
template <int K>
__global__ void k_gemm_scale(const float* __restrict__ X, const float* __restrict__ W,
                             const float* __restrict__ dinv, float* __restrict__ out) {
  __shared__ float aT[16][68];
  __shared__ float bS[16][64];
  const int t = threadIdx.x;
  const int row0 = blockIdx.x * 64;
  const int ty = t >> 4, tx = t & 15;

  float acc[4][4] = {};

  for (int k0 = 0; k0 < K; k0 += 16) {
    {
      int r = t >> 2, c = t & 3;
      int row = row0 + r;
      int rr = row < N_NODES ? row : N_NODES - 1;
      const float4 v = *reinterpret_cast<const float4*>(&X[(size_t)rr * K + k0 + c * 4]);
      aT[c * 4 + 0][r] = v.x;
      aT[c * 4 + 1][r] = v.y;
      aT[c * 4 + 2][r] = v.z;
      aT[c * 4 + 3][r] = v.w;
    }
    {
      int kr = t >> 4, c = (t & 15) * 4;
      *reinterpret_cast<float4*>(&bS[kr][c]) =
          *reinterpret_cast<const float4*>(&W[(size_t)(k0 + kr) * 64 + c]);
    }
    __syncthreads();
#pragma unroll
    for (int k = 0; k < 16; ++k) {
      float4 a = *reinterpret_cast<const float4*>(&aT[k][ty * 4]);
      float4 b = *reinterpret_cast<const float4*>(&bS[k][tx * 4]);
      float av[4] = {a.x, a.y, a.z, a.w};
      float bv[4] = {b.x, b.y, b.z, b.w};
#pragma unroll
      for (int i = 0; i < 4; ++i)
#pragma unroll
        for (int j = 0; j < 4; ++j) acc[i][j] += av[i] * bv[j];
    }
    __syncthreads();
  }

#pragma unroll
  for (int i = 0; i < 4; ++i) {
    int row = row0 + ty * 4 + i;
    if (row < N_NODES) {
      float s = dinv[row];
      float4 o;
      o.x = acc[i][0] * s; o.y = acc[i][1] * s; o.z = acc[i][2] * s; o.w = acc[i][3] * s;
      *reinterpret_cast<float4*>(&out[(size_t)row * 64 + tx * 4]) = o;
    }
  }
}

// ---------------- CSR gather-aggregate, fused epilogue ----------------
// h is already dinv-scaled (h' = dinv * (x@W)). For node v:
//   acc = h'[v] + sum_{e in CSR[v]} h'[col[e]]
//   val = relu(dinv[v]*acc + bias)
// FINAL=false: write val row.  FINAL=true: out[v] = sigmoid(val . Wc + bc)
template <bool FINAL>
__global__ void k_aggregate(const float* __restrict__ h, const int* __restrict__ rowptr,
                            const int* __restrict__ col, const float* __restrict__ dinv,
                            const float* __restrict__ bias, const float* __restrict__ Wc,
                            const float* __restrict__ bc, float* __restrict__ out) {
  int v = blockIdx.x * 4 + (threadIdx.x >> 6);
  int lane = threadIdx.x & 63;
  if (v >= N_NODES) return;

  int e = rowptr[v], end = rowptr[v + 1];
  float acc = h[(size_t)v * 64 + lane];  // self-loop term

  for (; e + 4 <= end; e += 4) {
    int s0 = col[e], s1 = col[e + 1], s2 = col[e + 2], s3 = col[e + 3];
    float a0 = h[(size_t)s0 * 64 + lane];
    float a1 = h[(size_t)s1 * 64 + lane];
    float a2 = h[(size_t)s2 * 64 + lane];
    float a3 = h[(size_t)s3 * 64 + lane];
    acc += (a0 + a1) + (a2 + a3);
  }
  for (; e < end; ++e) acc += h[(size_t)col[e] * 64 + lane];

  float val = fmaxf(dinv[v] * acc + bias[lane], 0.0f);
  if (!FINAL) {
    out[(size_t)v * 64 + lane] = val;
  } else {
    float p = val * Wc[lane];
#pragma unroll
    for (int off = 32; off; off >>= 1) p += __shfl_down(p, off);
    if (lane == 0) out[v] = 1.0f / (1.0f + expf(-(p + bc[0])));
  }
}

extern "C" void kernel_launch(void* const* d_in, const int* in_sizes, int n_in,
                              void* d_out, int out_size, void* d_ws, size_t ws_size,
                              hipStream_t stream) {
  const float* x  = (const float*)d_in[0];
  const int*   ei = (const int*)d_in[1];
  const float* W1 = (const float*)d_in[2];
  const float* b1 = (const float*)d_in[3];
  const float* W2 = (const float*)d_in[4];
  const float* b2 = (const float*)d_in[5];
  const float* Wc = (const float*)d_in[6];
  const float* bc = (const float*)d_in[7];
  float* out = (float*)d_out;

  const int* src = ei;
  const int* dst = ei + N_EDGES;

  // workspace layout (element offsets, 4B each)
  int*   cnt    = (int*)d_ws;                       // 50176
  int*   cursor = cnt + 50176;                      // 50176  (adjacent: one memset)
  int*   rowptr = cursor + 50176;                   // 50432 (needs 50001)
  int*   colidx = rowptr + 50432;                   // 800000
  float* dinv   = (float*)(colidx + 800000);        // 50176
  float* A      = dinv + 50176;                     // 3.2M
  float* B      = A + (size_t)N_NODES * 64;         // 3.2M

  // CSR build
  hipMemsetAsync(cnt, 0, 2 * 50176 * sizeof(int), stream);  // cnt + cursor
  k_hist<<<(N_EDGES + 255) / 256, 256, 0, stream>>>(dst, cnt);
  k_scan<<<1, 1024, 0, stream>>>(cnt, rowptr);
  k_dinv<<<(N_NODES + 255) / 256, 256, 0, stream>>>(cnt, dinv);
  k_fill<<<(N_EDGES + 255) / 256, 256, 0, stream>>>(src, dst, rowptr, cursor, colidx);

  // layer 1
  k_gemm_scale<IN_DIM><<<(N_NODES + 63) / 64, 256, 0, stream>>>(x, W1, dinv, A);
  k_aggregate<false><<<(N_NODES + 3) / 4, 256, 0, stream>>>(A, rowptr, colidx, dinv, b1,
                                                            nullptr, nullptr, B);
  // layer 2
  k_gemm_scale<HID><<<(N_NODES + 63) / 64, 256, 0, stream>>>(B, W2, dinv, A);
  k_aggregate<true><<<(N_NODES + 3) / 4, 256, 0, stream>>>(A, rowptr, colidx, dinv, b2,
                                                           Wc, bc, out);
}

// Round 3
// 212.593 us; speedup vs baseline: 2.2439x; 1.4297x over previous
//
#include <hip/hip_runtime.h>
#include <math.h>

#define N_NODES 50000
#define N_EDGES 800000
#define IN_DIM 256
#define HID 64
#define NB_SCAN ((N_NODES + 255) / 256)  // 196

// ---------------- CSR build ----------------
__global__ void k_hist(const int* __restrict__ dst, int* __restrict__ cnt) {
  int e = blockIdx.x * 256 + threadIdx.x;
  if (e < N_EDGES) atomicAdd(&cnt[dst[e]], 1);
}

// phase a: per-block (256-elem chunk) sum of cnt
__global__ void k_scan_a(const int* __restrict__ cnt, int* __restrict__ bsum) {
  int idx = blockIdx.x * 256 + threadIdx.x;
  int v = (idx < N_NODES) ? cnt[idx] : 0;
#pragma unroll
  for (int off = 32; off; off >>= 1) v += __shfl_down(v, off);
  __shared__ int part[4];
  if ((threadIdx.x & 63) == 0) part[threadIdx.x >> 6] = v;
  __syncthreads();
  if (threadIdx.x == 0) bsum[blockIdx.x] = part[0] + part[1] + part[2] + part[3];
}

// phase b: single small block scans the NB_SCAN block sums (exclusive)
__global__ void k_scan_b(int* __restrict__ bsum) {
  __shared__ int s[256];
  int t = threadIdx.x;
  s[t] = (t < NB_SCAN) ? bsum[t] : 0;
  __syncthreads();
  for (int d = 1; d < 256; d <<= 1) {
    int v = s[t];
    int a = (t >= d) ? s[t - d] : 0;
    __syncthreads();
    s[t] = v + a;
    __syncthreads();
  }
  if (t < NB_SCAN) bsum[t] = (t == 0) ? 0 : s[t - 1];
}

// phase c: block-local exclusive scan + block offset -> rowptr, cursor, dinv
__global__ void k_scan_c(const int* __restrict__ cnt, const int* __restrict__ bsum,
                         int* __restrict__ rowptr, int* __restrict__ cursor,
                         float* __restrict__ dinv) {
  __shared__ int s[256];
  int t = threadIdx.x;
  int idx = blockIdx.x * 256 + t;
  int c = (idx < N_NODES) ? cnt[idx] : 0;
  s[t] = c;
  __syncthreads();
  for (int d = 1; d < 256; d <<= 1) {
    int v = s[t];
    int a = (t >= d) ? s[t - d] : 0;
    __syncthreads();
    s[t] = v + a;
    __syncthreads();
  }
  if (idx < N_NODES) {
    int ex = bsum[blockIdx.x] + s[t] - c;
    rowptr[idx] = ex;
    cursor[idx] = ex;
    dinv[idx] = rsqrtf((float)(c + 1));  // +1 self-loop
  }
  if (idx == 0) rowptr[N_NODES] = N_EDGES;
}

// fill: cursor holds running write positions (starts at rowptr)
__global__ void k_fill(const int* __restrict__ src, const int* __restrict__ dst,
                       int* __restrict__ cursor, int* __restrict__ col) {
  int e = blockIdx.x * 256 + threadIdx.x;
  if (e < N_EDGES) {
    int pos = atomicAdd(&cursor[dst[e]], 1);
    col[pos] = src[e];
  }
}

// ---------------- GEMM: out[r][c] = dinv[r] * sum_k X[r][k] * W[k][c], C=64 ----------------
template <int K>
__global__ void k_gemm_scale(const float* __restrict__ X, const float* __restrict__ W,
                             const float* __restrict__ dinv, float* __restrict__ out) {
  __shared__ float aT[16][68];
  __shared__ float bS[16][64];
  const int t = threadIdx.x;
  const int row0 = blockIdx.x * 64;
  const int ty = t >> 4, tx = t & 15;

  float acc[4][4] = {};

  for (int k0 = 0; k0 < K; k0 += 16) {
    {
      int r = t >> 2, c = t & 3;
      int row = row0 + r;
      int rr = row < N_NODES ? row : N_NODES - 1;
      const float4 v = *reinterpret_cast<const float4*>(&X[(size_t)rr * K + k0 + c * 4]);
      aT[c * 4 + 0][r] = v.x;
      aT[c * 4 + 1][r] = v.y;
      aT[c * 4 + 2][r] = v.z;
      aT[c * 4 + 3][r] = v.w;
    }
    {
      int kr = t >> 4, c = (t & 15) * 4;
      *reinterpret_cast<float4*>(&bS[kr][c]) =
          *reinterpret_cast<const float4*>(&W[(size_t)(k0 + kr) * 64 + c]);
    }
    __syncthreads();
#pragma unroll
    for (int k = 0; k < 16; ++k) {
      float4 a = *reinterpret_cast<const float4*>(&aT[k][ty * 4]);
      float4 b = *reinterpret_cast<const float4*>(&bS[k][tx * 4]);
      float av[4] = {a.x, a.y, a.z, a.w};
      float bv[4] = {b.x, b.y, b.z, b.w};
#pragma unroll
      for (int i = 0; i < 4; ++i)
#pragma unroll
        for (int j = 0; j < 4; ++j) acc[i][j] += av[i] * bv[j];
    }
    __syncthreads();
  }

#pragma unroll
  for (int i = 0; i < 4; ++i) {
    int row = row0 + ty * 4 + i;
    if (row < N_NODES) {
      float s = dinv[row];
      float4 o;
      o.x = acc[i][0] * s; o.y = acc[i][1] * s; o.z = acc[i][2] * s; o.w = acc[i][3] * s;
      *reinterpret_cast<float4*>(&out[(size_t)row * 64 + tx * 4]) = o;
    }
  }
}

// ---------------- CSR gather-aggregate, fused epilogue ----------------
template <bool FINAL>
__global__ void k_aggregate(const float* __restrict__ h, const int* __restrict__ rowptr,
                            const int* __restrict__ col, const float* __restrict__ dinv,
                            const float* __restrict__ bias, const float* __restrict__ Wc,
                            const float* __restrict__ bc, float* __restrict__ out) {
  int v = blockIdx.x * 4 + (threadIdx.x >> 6);
  int lane = threadIdx.x & 63;
  if (v >= N_NODES) return;

  int e = rowptr[v], end = rowptr[v + 1];
  float acc = h[(size_t)v * 64 + lane];  // self-loop term

  for (; e + 4 <= end; e += 4) {
    int s0 = col[e], s1 = col[e + 1], s2 = col[e + 2], s3 = col[e + 3];
    float a0 = h[(size_t)s0 * 64 + lane];
    float a1 = h[(size_t)s1 * 64 + lane];
    float a2 = h[(size_t)s2 * 64 + lane];
    float a3 = h[(size_t)s3 * 64 + lane];
    acc += (a0 + a1) + (a2 + a3);
  }
  for (; e < end; ++e) acc += h[(size_t)col[e] * 64 + lane];

  float val = fmaxf(dinv[v] * acc + bias[lane], 0.0f);
  if (!FINAL) {
    out[(size_t)v * 64 + lane] = val;
  } else {
    float p = val * Wc[lane];
#pragma unroll
    for (int off = 32; off; off >>= 1) p += __shfl_down(p, off);
    if (lane == 0) out[v] = 1.0f / (1.0f + expf(-(p + bc[0])));
  }
}

extern "C" void kernel_launch(void* const* d_in, const int* in_sizes, int n_in,
                              void* d_out, int out_size, void* d_ws, size_t ws_size,
                              hipStream_t stream) {
  const float* x  = (const float*)d_in[0];
  const int*   ei = (const int*)d_in[1];
  const float* W1 = (const float*)d_in[2];
  const float* b1 = (const float*)d_in[3];
  const float* W2 = (const float*)d_in[4];
  const float* b2 = (const float*)d_in[5];
  const float* Wc = (const float*)d_in[6];
  const float* bc = (const float*)d_in[7];
  float* out = (float*)d_out;

  const int* src = ei;
  const int* dst = ei + N_EDGES;

  // workspace layout (element offsets, 4B each)
  int*   cnt    = (int*)d_ws;                       // 50176
  int*   cursor = cnt + 50176;                      // 50176
  int*   rowptr = cursor + 50176;                   // 50432 (needs 50001)
  int*   bsum   = rowptr + 50432;                   // 256
  int*   colidx = bsum + 256;                       // 800000
  float* dinv   = (float*)(colidx + 800000);        // 50176
  float* A      = dinv + 50176;                     // 3.2M
  float* B      = A + (size_t)N_NODES * 64;         // 3.2M

  // CSR build
  hipMemsetAsync(cnt, 0, 50176 * sizeof(int), stream);
  k_hist<<<(N_EDGES + 255) / 256, 256, 0, stream>>>(dst, cnt);
  k_scan_a<<<NB_SCAN, 256, 0, stream>>>(cnt, bsum);
  k_scan_b<<<1, 256, 0, stream>>>(bsum);
  k_scan_c<<<NB_SCAN, 256, 0, stream>>>(cnt, bsum, rowptr, cursor, dinv);
  k_fill<<<(N_EDGES + 255) / 256, 256, 0, stream>>>(src, dst, cursor, colidx);

  // layer 1
  k_gemm_scale<IN_DIM><<<(N_NODES + 63) / 64, 256, 0, stream>>>(x, W1, dinv, A);
  k_aggregate<false><<<(N_NODES + 3) / 4, 256, 0, stream>>>(A, rowptr, colidx, dinv, b1,
                                                            nullptr, nullptr, B);
  // layer 2
  k_gemm_scale<HID><<<(N_NODES + 63) / 64, 256, 0, stream>>>(B, W2, dinv, A);
  k_aggregate<true><<<(N_NODES + 3) / 4, 256, 0, stream>>>(A, rowptr, colidx, dinv, b2,
                                                           Wc, bc, out);
}

// Round 4
// 170.706 us; speedup vs baseline: 2.7945x; 1.2454x over previous
//
#include <hip/hip_runtime.h>
#include <math.h>

#define N_NODES 50000
#define N_EDGES 800000
#define IN_DIM 256
#define HID 64
#define BKT 256                                   // nodes per bucket
#define NBKT ((N_NODES + BKT - 1) / BKT)          // 196
#define CHUNK 4096
#define NCH ((N_EDGES + CHUNK - 1) / CHUNK)       // 196

// ---------------- kA: coarse bucket histogram ----------------
__global__ void k_bhist(const int* __restrict__ dst, int* __restrict__ bcnt) {
  __shared__ int h[NBKT];
  const int t = threadIdx.x;
  for (int i = t; i < NBKT; i += 256) h[i] = 0;
  __syncthreads();
  const int base = blockIdx.x * CHUNK;
#pragma unroll
  for (int i = 0; i < CHUNK / 256; ++i) {
    int e = base + i * 256 + t;
    if (e < N_EDGES) atomicAdd(&h[dst[e] >> 8], 1);
  }
  __syncthreads();
  for (int i = t; i < NBKT; i += 256)
    if (h[i]) atomicAdd(&bcnt[i], h[i]);
}

// ---------------- kB: scan bucket counts -> bptr, bcur ----------------
__global__ void k_bscan(const int* __restrict__ bcnt, int* __restrict__ bptr,
                        int* __restrict__ bcur) {
  __shared__ int s[256];
  const int t = threadIdx.x;
  s[t] = (t < NBKT) ? bcnt[t] : 0;
  __syncthreads();
  for (int d = 1; d < 256; d <<= 1) {
    int v = s[t];
    int a = (t >= d) ? s[t - d] : 0;
    __syncthreads();
    s[t] = v + a;
    __syncthreads();
  }
  if (t < NBKT) {
    int ex = (t == 0) ? 0 : s[t - 1];
    bptr[t] = ex;
    bcur[t] = ex;
  } else if (t == NBKT) {
    bptr[NBKT] = N_EDGES;
  }
}

// ---------------- kC: multisplit into bucket regions (packed u32) ----------------
__global__ void k_split(const int* __restrict__ src, const int* __restrict__ dst,
                        int* __restrict__ bcur, unsigned* __restrict__ ebuf) {
  __shared__ int cnt[NBKT];
  __shared__ int cur[NBKT];
  const int t = threadIdx.x;
  for (int i = t; i < NBKT; i += 256) cnt[i] = 0;
  __syncthreads();
  const int base = blockIdx.x * CHUNK;
#pragma unroll
  for (int i = 0; i < CHUNK / 256; ++i) {
    int e = base + i * 256 + t;
    if (e < N_EDGES) atomicAdd(&cnt[dst[e] >> 8], 1);
  }
  __syncthreads();
  for (int i = t; i < NBKT; i += 256) {
    int c = cnt[i];
    cur[i] = c ? atomicAdd(&bcur[i], c) : 0;
  }
  __syncthreads();
#pragma unroll
  for (int i = 0; i < CHUNK / 256; ++i) {
    int e = base + i * 256 + t;
    if (e < N_EDGES) {
      int d = dst[e];
      int p = atomicAdd(&cur[d >> 8], 1);
      ebuf[p] = ((unsigned)src[e] << 8) | (unsigned)(d & 255);
    }
  }
}

// ---------------- kD: per-bucket fine CSR: rowptr, dinv, colidx ----------------
__global__ void k_bucket(const unsigned* __restrict__ ebuf, const int* __restrict__ bptr,
                         int* __restrict__ rowptr, int* __restrict__ colidx,
                         float* __restrict__ dinv) {
  __shared__ int cnt[BKT];
  __shared__ int off[BKT];
  const int b = blockIdx.x, t = threadIdx.x;
  const int beg = bptr[b], end = bptr[b + 1];
  cnt[t] = 0;
  __syncthreads();
  for (int i = beg + t; i < end; i += 256) atomicAdd(&cnt[ebuf[i] & 255], 1);
  __syncthreads();
  off[t] = cnt[t];
  __syncthreads();
  for (int d = 1; d < 256; d <<= 1) {
    int v = off[t];
    int a = (t >= d) ? off[t - d] : 0;
    __syncthreads();
    off[t] = v + a;
    __syncthreads();
  }
  const int node = b * BKT + t;
  const int ex = beg + off[t] - cnt[t];  // exclusive scan + bucket base
  if (node < N_NODES) {
    rowptr[node] = ex;
    dinv[node] = rsqrtf((float)(cnt[t] + 1));  // +1 self-loop
    if (node == N_NODES - 1) rowptr[N_NODES] = N_EDGES;
  }
  __syncthreads();
  off[t] = ex;  // reuse as per-node cursor
  __syncthreads();
  for (int i = beg + t; i < end; i += 256) {
    unsigned p = ebuf[i];
    int pos = atomicAdd(&off[p & 255], 1);
    colidx[pos] = (int)(p >> 8);
  }
}

// ---------------- GEMM: out[r][c] = dinv[r] * sum_k X[r][k] * W[k][c], C=64 ----------------
template <int K>
__global__ void k_gemm_scale(const float* __restrict__ X, const float* __restrict__ W,
                             const float* __restrict__ dinv, float* __restrict__ out) {
  __shared__ float aT[16][68];
  __shared__ float bS[16][64];
  const int t = threadIdx.x;
  const int row0 = blockIdx.x * 64;
  const int ty = t >> 4, tx = t & 15;

  float acc[4][4] = {};

  for (int k0 = 0; k0 < K; k0 += 16) {
    {
      int r = t >> 2, c = t & 3;
      int row = row0 + r;
      int rr = row < N_NODES ? row : N_NODES - 1;
      const float4 v = *reinterpret_cast<const float4*>(&X[(size_t)rr * K + k0 + c * 4]);
      aT[c * 4 + 0][r] = v.x;
      aT[c * 4 + 1][r] = v.y;
      aT[c * 4 + 2][r] = v.z;
      aT[c * 4 + 3][r] = v.w;
    }
    {
      int kr = t >> 4, c = (t & 15) * 4;
      *reinterpret_cast<float4*>(&bS[kr][c]) =
          *reinterpret_cast<const float4*>(&W[(size_t)(k0 + kr) * 64 + c]);
    }
    __syncthreads();
#pragma unroll
    for (int k = 0; k < 16; ++k) {
      float4 a = *reinterpret_cast<const float4*>(&aT[k][ty * 4]);
      float4 b = *reinterpret_cast<const float4*>(&bS[k][tx * 4]);
      float av[4] = {a.x, a.y, a.z, a.w};
      float bv[4] = {b.x, b.y, b.z, b.w};
#pragma unroll
      for (int i = 0; i < 4; ++i)
#pragma unroll
        for (int j = 0; j < 4; ++j) acc[i][j] += av[i] * bv[j];
    }
    __syncthreads();
  }

#pragma unroll
  for (int i = 0; i < 4; ++i) {
    int row = row0 + ty * 4 + i;
    if (row < N_NODES) {
      float s = dinv[row];
      float4 o;
      o.x = acc[i][0] * s; o.y = acc[i][1] * s; o.z = acc[i][2] * s; o.w = acc[i][3] * s;
      *reinterpret_cast<float4*>(&out[(size_t)row * 64 + tx * 4]) = o;
    }
  }
}

// ---------------- CSR gather-aggregate, fused epilogue ----------------
template <bool FINAL>
__global__ void k_aggregate(const float* __restrict__ h, const int* __restrict__ rowptr,
                            const int* __restrict__ col, const float* __restrict__ dinv,
                            const float* __restrict__ bias, const float* __restrict__ Wc,
                            const float* __restrict__ bc, float* __restrict__ out) {
  int v = blockIdx.x * 4 + (threadIdx.x >> 6);
  int lane = threadIdx.x & 63;
  if (v >= N_NODES) return;

  int e = rowptr[v], end = rowptr[v + 1];
  float acc0 = h[(size_t)v * 64 + lane];  // self-loop term
  float acc1 = 0.0f;

  for (; e + 8 <= end; e += 8) {
    int s0 = col[e],     s1 = col[e + 1], s2 = col[e + 2], s3 = col[e + 3];
    int s4 = col[e + 4], s5 = col[e + 5], s6 = col[e + 6], s7 = col[e + 7];
    float a0 = h[(size_t)s0 * 64 + lane];
    float a1 = h[(size_t)s1 * 64 + lane];
    float a2 = h[(size_t)s2 * 64 + lane];
    float a3 = h[(size_t)s3 * 64 + lane];
    float a4 = h[(size_t)s4 * 64 + lane];
    float a5 = h[(size_t)s5 * 64 + lane];
    float a6 = h[(size_t)s6 * 64 + lane];
    float a7 = h[(size_t)s7 * 64 + lane];
    acc0 += (a0 + a1) + (a2 + a3);
    acc1 += (a4 + a5) + (a6 + a7);
  }
  for (; e < end; ++e) acc0 += h[(size_t)col[e] * 64 + lane];
  float acc = acc0 + acc1;

  float val = fmaxf(dinv[v] * acc + bias[lane], 0.0f);
  if (!FINAL) {
    out[(size_t)v * 64 + lane] = val;
  } else {
    float p = val * Wc[lane];
#pragma unroll
    for (int off = 32; off; off >>= 1) p += __shfl_down(p, off);
    if (lane == 0) out[v] = 1.0f / (1.0f + expf(-(p + bc[0])));
  }
}

extern "C" void kernel_launch(void* const* d_in, const int* in_sizes, int n_in,
                              void* d_out, int out_size, void* d_ws, size_t ws_size,
                              hipStream_t stream) {
  const float* x  = (const float*)d_in[0];
  const int*   ei = (const int*)d_in[1];
  const float* W1 = (const float*)d_in[2];
  const float* b1 = (const float*)d_in[3];
  const float* W2 = (const float*)d_in[4];
  const float* b2 = (const float*)d_in[5];
  const float* Wc = (const float*)d_in[6];
  const float* bc = (const float*)d_in[7];
  float* out = (float*)d_out;

  const int* src = ei;
  const int* dst = ei + N_EDGES;

  // workspace layout (element offsets, 4B each)
  int*   bcnt   = (int*)d_ws;                       // 256
  int*   bptr   = bcnt + 256;                       // 512 (needs 197)
  int*   bcur   = bptr + 512;                       // 256
  int*   rowptr = bcur + 256;                       // 50432 (needs 50001)
  int*   colidx = rowptr + 50432;                   // 800000
  float* dinv   = (float*)(colidx + 800000);        // 50176
  float* A      = dinv + 50176;                     // 3.2M
  float* B      = A + (size_t)N_NODES * 64;         // 3.2M
  unsigned* ebuf = (unsigned*)B;                    // aliases B (dead until agg1)

  // CSR build (bucketed counting sort; all heavy writes block-local + line-dense)
  hipMemsetAsync(bcnt, 0, 256 * sizeof(int), stream);
  k_bhist<<<NCH, 256, 0, stream>>>(dst, bcnt);
  k_bscan<<<1, 256, 0, stream>>>(bcnt, bptr, bcur);
  k_split<<<NCH, 256, 0, stream>>>(src, dst, bcur, ebuf);
  k_bucket<<<NBKT, 256, 0, stream>>>(ebuf, bptr, rowptr, colidx, dinv);

  // layer 1
  k_gemm_scale<IN_DIM><<<(N_NODES + 63) / 64, 256, 0, stream>>>(x, W1, dinv, A);
  k_aggregate<false><<<(N_NODES + 3) / 4, 256, 0, stream>>>(A, rowptr, colidx, dinv, b1,
                                                            nullptr, nullptr, B);
  // layer 2
  k_gemm_scale<HID><<<(N_NODES + 63) / 64, 256, 0, stream>>>(B, W2, dinv, A);
  k_aggregate<true><<<(N_NODES + 3) / 4, 256, 0, stream>>>(A, rowptr, colidx, dinv, b2,
                                                           Wc, bc, out);
}

// Round 5
// 154.995 us; speedup vs baseline: 3.0777x; 1.1014x over previous
//
#include <hip/hip_runtime.h>
#include <math.h>

#define N_NODES 50000
#define N_EDGES 800000
#define IN_DIM 256
#define HID 64
#define BKT 256
#define NBKT ((N_NODES + BKT - 1) / BKT)          // 196
#define CHUNK 4096
#define NCH ((N_EDGES + CHUNK - 1) / CHUNK)       // 196

typedef short short8v __attribute__((ext_vector_type(8)));
typedef float f32x4 __attribute__((ext_vector_type(4)));

__device__ __forceinline__ unsigned short f2bf(float f) {
  unsigned u = __builtin_bit_cast(unsigned, f);
  u += 0x7FFFu + ((u >> 16) & 1u);  // RNE
  return (unsigned short)(u >> 16);
}
__device__ __forceinline__ float bf2f(unsigned short h) {
  unsigned u = (unsigned)h << 16;
  return __builtin_bit_cast(float, u);
}
__device__ __forceinline__ unsigned pack2(float a, float b) {
  return (unsigned)f2bf(a) | ((unsigned)f2bf(b) << 16);
}

// ---------------- misc ----------------
__global__ void k_zero(int* p) { p[threadIdx.x] = 0; }

// ---------------- kA: coarse bucket histogram ----------------
__global__ void k_bhist(const int* __restrict__ dst, int* __restrict__ bcnt) {
  __shared__ int h[NBKT];
  const int t = threadIdx.x;
  for (int i = t; i < NBKT; i += 256) h[i] = 0;
  __syncthreads();
  const int base = blockIdx.x * CHUNK;
#pragma unroll
  for (int i = 0; i < CHUNK / 256; ++i) {
    int e = base + i * 256 + t;
    if (e < N_EDGES) atomicAdd(&h[dst[e] >> 8], 1);
  }
  __syncthreads();
  for (int i = t; i < NBKT; i += 256)
    if (h[i]) atomicAdd(&bcnt[i], h[i]);
}

// ---------------- kB: scan bucket counts -> bptr, bcur ----------------
__global__ void k_bscan(const int* __restrict__ bcnt, int* __restrict__ bptr,
                        int* __restrict__ bcur) {
  __shared__ int s[256];
  const int t = threadIdx.x;
  s[t] = (t < NBKT) ? bcnt[t] : 0;
  __syncthreads();
  for (int d = 1; d < 256; d <<= 1) {
    int v = s[t];
    int a = (t >= d) ? s[t - d] : 0;
    __syncthreads();
    s[t] = v + a;
    __syncthreads();
  }
  if (t < NBKT) {
    int ex = (t == 0) ? 0 : s[t - 1];
    bptr[t] = ex;
    bcur[t] = ex;
  } else if (t == NBKT) {
    bptr[NBKT] = N_EDGES;
  }
}

// ---------------- kC: multisplit into bucket regions (packed u32) ----------------
__global__ void k_split(const int* __restrict__ src, const int* __restrict__ dst,
                        int* __restrict__ bcur, unsigned* __restrict__ ebuf) {
  __shared__ int cnt[NBKT];
  __shared__ int cur[NBKT];
  const int t = threadIdx.x;
  for (int i = t; i < NBKT; i += 256) cnt[i] = 0;
  __syncthreads();
  const int base = blockIdx.x * CHUNK;
#pragma unroll
  for (int i = 0; i < CHUNK / 256; ++i) {
    int e = base + i * 256 + t;
    if (e < N_EDGES) atomicAdd(&cnt[dst[e] >> 8], 1);
  }
  __syncthreads();
  for (int i = t; i < NBKT; i += 256) {
    int c = cnt[i];
    cur[i] = c ? atomicAdd(&bcur[i], c) : 0;
  }
  __syncthreads();
#pragma unroll
  for (int i = 0; i < CHUNK / 256; ++i) {
    int e = base + i * 256 + t;
    if (e < N_EDGES) {
      int d = dst[e];
      int p = atomicAdd(&cur[d >> 8], 1);
      ebuf[p] = ((unsigned)src[e] << 8) | (unsigned)(d & 255);
    }
  }
}

// ---------------- kD: per-bucket fine CSR ----------------
__global__ void k_bucket(const unsigned* __restrict__ ebuf, const int* __restrict__ bptr,
                         int* __restrict__ rowptr, int* __restrict__ colidx,
                         float* __restrict__ dinv) {
  __shared__ int cnt[BKT];
  __shared__ int off[BKT];
  const int b = blockIdx.x, t = threadIdx.x;
  const int beg = bptr[b], end = bptr[b + 1];
  cnt[t] = 0;
  __syncthreads();
  for (int i = beg + t; i < end; i += 256) atomicAdd(&cnt[ebuf[i] & 255], 1);
  __syncthreads();
  off[t] = cnt[t];
  __syncthreads();
  for (int d = 1; d < 256; d <<= 1) {
    int v = off[t];
    int a = (t >= d) ? off[t - d] : 0;
    __syncthreads();
    off[t] = v + a;
    __syncthreads();
  }
  const int node = b * BKT + t;
  const int ex = beg + off[t] - cnt[t];
  if (node < N_NODES) {
    rowptr[node] = ex;
    dinv[node] = rsqrtf((float)(cnt[t] + 1));
    if (node == N_NODES - 1) rowptr[N_NODES] = N_EDGES;
  }
  __syncthreads();
  off[t] = ex;
  __syncthreads();
  for (int i = beg + t; i < end; i += 256) {
    unsigned p = ebuf[i];
    int pos = atomicAdd(&off[p & 255], 1);
    colidx[pos] = (int)(p >> 8);
  }
}

// ---------------- weight prep: f32 [K][64] -> bf16 transposed [64][K] ----------------
__global__ void k_wprep(const float* __restrict__ W1, const float* __restrict__ W2,
                        unsigned short* __restrict__ Wt1, unsigned short* __restrict__ Wt2) {
  const int t = threadIdx.x;
  if (blockIdx.x == 0) {
    for (int j = 0; j < 64; ++j) {
      int lin = j * 256 + t;
      int k = lin >> 6, c = lin & 63;
      Wt1[c * 256 + k] = f2bf(W1[lin]);
    }
  } else {
    for (int j = 0; j < 16; ++j) {
      int lin = j * 256 + t;
      int k = lin >> 6, c = lin & 63;
      Wt2[c * 64 + k] = f2bf(W2[lin]);
    }
  }
}

// ---------------- MFMA GEMM: out_bf[r][c] = bf16( dinv[r] * sum_k X[r][k]*W[k][c] ) ----------------
// 256 threads = 4 waves; block tile 64 rows x 64 cols; 16x16x32 bf16 MFMA.
// A and B fragments use the SAME lane->k bijection (k = (lane>>4)*8 + i), so the
// contraction is correct regardless of the HW's internal k permutation.
// C/D layout (verified): col = lane&15, row = (lane>>4)*4 + reg.
template <int K, bool XF32>
__global__ void k_gemm_mfma(const void* __restrict__ Xv, const unsigned short* __restrict__ Wtg,
                            const float* __restrict__ dinv, unsigned short* __restrict__ out) {
  __shared__ unsigned short Ax[64][72];       // current 64-wide K chunk of X, bf16
  __shared__ unsigned short Wt[64][K + 8];    // full W transposed [col][k], bf16
  const int t = threadIdx.x;
  const int lane = t & 63, wv = t >> 6;
  const int row0 = blockIdx.x * 64;

  // stage Wt (whole K)
#pragma unroll
  for (int j = 0; j < K / 32; ++j) {
    int lin = (j * 256 + t) * 8;
    int r = lin / K, c = lin % K;
    *reinterpret_cast<short8v*>(&Wt[r][c]) =
        *reinterpret_cast<const short8v*>(&Wtg[lin]);
  }

  f32x4 acc[4] = {};

  for (int kc = 0; kc < K; kc += 64) {
    __syncthreads();  // protect Ax overwrite (and cover Wt on first iter)
    if (XF32) {
      const float* X = (const float*)Xv;
#pragma unroll
      for (int j = 0; j < 4; ++j) {
        int lin = (j * 256 + t) * 4;           // 0..4095
        int r = lin >> 6, c = lin & 63;
        int rg = row0 + r; if (rg > N_NODES - 1) rg = N_NODES - 1;
        const float4 v = *reinterpret_cast<const float4*>(&X[(size_t)rg * K + kc + c]);
        uint2 w; w.x = pack2(v.x, v.y); w.y = pack2(v.z, v.w);
        *reinterpret_cast<uint2*>(&Ax[r][c]) = w;
      }
    } else {
#pragma unroll
      for (int j = 0; j < 2; ++j) {
        int lin = (j * 256 + t) * 8;           // 0..4095
        int r = lin >> 6, c = lin & 63;
        int rg = row0 + r; if (rg > N_NODES - 1) rg = N_NODES - 1;
        *reinterpret_cast<short8v*>(&Ax[r][c]) =
            *reinterpret_cast<const short8v*>(&((const unsigned short*)Xv)[(size_t)rg * 64 + c]);
      }
    }
    __syncthreads();
#pragma unroll
    for (int k0 = 0; k0 < 64; k0 += 32) {
      short8v a = *reinterpret_cast<const short8v*>(&Ax[wv * 16 + (lane & 15)][k0 + (lane >> 4) * 8]);
#pragma unroll
      for (int n = 0; n < 4; ++n) {
        short8v b = *reinterpret_cast<const short8v*>(&Wt[n * 16 + (lane & 15)][kc + k0 + (lane >> 4) * 8]);
        acc[n] = __builtin_amdgcn_mfma_f32_16x16x32_bf16(a, b, acc[n], 0, 0, 0);
      }
    }
  }

  // epilogue: scale by dinv[row], store bf16
  const int r0 = row0 + wv * 16;
#pragma unroll
  for (int j = 0; j < 4; ++j) {
    int r = r0 + (lane >> 4) * 4 + j;
    if (r < N_NODES) {
      float s = dinv[r];
#pragma unroll
      for (int n = 0; n < 4; ++n)
        out[(size_t)r * 64 + n * 16 + (lane & 15)] = f2bf(acc[n][j] * s);
    }
  }
}

// ---------------- CSR gather-aggregate (bf16 h), fused epilogue ----------------
template <bool FINAL>
__global__ void k_aggregate(const unsigned short* __restrict__ h, const int* __restrict__ rowptr,
                            const int* __restrict__ col, const float* __restrict__ dinv,
                            const float* __restrict__ bias, const float* __restrict__ Wc,
                            const float* __restrict__ bc, void* __restrict__ outv) {
  int v = blockIdx.x * 4 + (threadIdx.x >> 6);
  int lane = threadIdx.x & 63;
  if (v >= N_NODES) return;

  int e = rowptr[v], end = rowptr[v + 1];
  float acc0 = bf2f(h[(size_t)v * 64 + lane]);  // self-loop term
  float acc1 = 0.0f;

  for (; e + 8 <= end; e += 8) {
    int s0 = col[e],     s1 = col[e + 1], s2 = col[e + 2], s3 = col[e + 3];
    int s4 = col[e + 4], s5 = col[e + 5], s6 = col[e + 6], s7 = col[e + 7];
    float a0 = bf2f(h[(size_t)s0 * 64 + lane]);
    float a1 = bf2f(h[(size_t)s1 * 64 + lane]);
    float a2 = bf2f(h[(size_t)s2 * 64 + lane]);
    float a3 = bf2f(h[(size_t)s3 * 64 + lane]);
    float a4 = bf2f(h[(size_t)s4 * 64 + lane]);
    float a5 = bf2f(h[(size_t)s5 * 64 + lane]);
    float a6 = bf2f(h[(size_t)s6 * 64 + lane]);
    float a7 = bf2f(h[(size_t)s7 * 64 + lane]);
    acc0 += (a0 + a1) + (a2 + a3);
    acc1 += (a4 + a5) + (a6 + a7);
  }
  for (; e < end; ++e) acc0 += bf2f(h[(size_t)col[e] * 64 + lane]);

  float val = fmaxf(dinv[v] * (acc0 + acc1) + bias[lane], 0.0f);
  if (!FINAL) {
    ((unsigned short*)outv)[(size_t)v * 64 + lane] = f2bf(val);
  } else {
    float p = val * Wc[lane];
#pragma unroll
    for (int off = 32; off; off >>= 1) p += __shfl_down(p, off);
    if (lane == 0) ((float*)outv)[v] = 1.0f / (1.0f + expf(-(p + bc[0])));
  }
}

extern "C" void kernel_launch(void* const* d_in, const int* in_sizes, int n_in,
                              void* d_out, int out_size, void* d_ws, size_t ws_size,
                              hipStream_t stream) {
  const float* x  = (const float*)d_in[0];
  const int*   ei = (const int*)d_in[1];
  const float* W1 = (const float*)d_in[2];
  const float* b1 = (const float*)d_in[3];
  const float* W2 = (const float*)d_in[4];
  const float* b2 = (const float*)d_in[5];
  const float* Wc = (const float*)d_in[6];
  const float* bc = (const float*)d_in[7];
  float* out = (float*)d_out;

  const int* src = ei;
  const int* dst = ei + N_EDGES;

  // workspace layout (u32 units)
  unsigned* w = (unsigned*)d_ws;
  int*   bcnt   = (int*)(w + 0);            // 256
  int*   bptr   = (int*)(w + 256);          // 512
  int*   bcur   = (int*)(w + 768);          // 256
  int*   rowptr = (int*)(w + 1024);         // 50432
  int*   colidx = (int*)(w + 51456);        // 800000
  unsigned* ebuf = w + 851456;              // 800000
  float* dinv   = (float*)(w + 1651456);    // 50176
  unsigned short* Wt1g = (unsigned short*)(w + 1701632);  // 16384 ush
  unsigned short* Wt2g = (unsigned short*)(w + 1709824);  // 4096 ush
  unsigned short* A_bf = (unsigned short*)(w + 1711872);  // 3.2M ush
  unsigned short* B_bf = (unsigned short*)(w + 3311872);  // 3.2M ush

  // CSR build
  k_zero<<<1, 256, 0, stream>>>(bcnt);
  k_bhist<<<NCH, 256, 0, stream>>>(dst, bcnt);
  k_bscan<<<1, 256, 0, stream>>>(bcnt, bptr, bcur);
  k_split<<<NCH, 256, 0, stream>>>(src, dst, bcur, ebuf);
  k_bucket<<<NBKT, 256, 0, stream>>>(ebuf, bptr, rowptr, colidx, dinv);

  // weights -> bf16 transposed
  k_wprep<<<2, 256, 0, stream>>>(W1, W2, Wt1g, Wt2g);

  const int NGB = (N_NODES + 63) / 64;  // 782
  // layer 1
  k_gemm_mfma<IN_DIM, true><<<NGB, 256, 0, stream>>>(x, Wt1g, dinv, A_bf);
  k_aggregate<false><<<(N_NODES + 3) / 4, 256, 0, stream>>>(A_bf, rowptr, colidx, dinv, b1,
                                                            nullptr, nullptr, B_bf);
  // layer 2
  k_gemm_mfma<HID, false><<<NGB, 256, 0, stream>>>(B_bf, Wt2g, dinv, A_bf);
  k_aggregate<true><<<(N_NODES + 3) / 4, 256, 0, stream>>>(A_bf, rowptr, colidx, dinv, b2,
                                                           Wc, bc, out);
}

// Round 6
// 129.172 us; speedup vs baseline: 3.6930x; 1.1999x over previous
//
#include <hip/hip_runtime.h>
#include <math.h>

#define N_NODES 50000
#define N_EDGES 800000
#define IN_DIM 256
#define HID 64
#define BKT 256
#define NBKT ((N_NODES + BKT - 1) / BKT)          // 196
#define CHUNK 4096
#define NCH ((N_EDGES + CHUNK - 1) / CHUNK)       // 196

typedef short short8v __attribute__((ext_vector_type(8)));
typedef float f32x4 __attribute__((ext_vector_type(4)));
typedef unsigned uint4v __attribute__((ext_vector_type(4)));

__device__ __forceinline__ unsigned short f2bf(float f) {
  unsigned u = __builtin_bit_cast(unsigned, f);
  u += 0x7FFFu + ((u >> 16) & 1u);  // RNE
  return (unsigned short)(u >> 16);
}
__device__ __forceinline__ unsigned pack2(float a, float b) {
  return (unsigned)f2bf(a) | ((unsigned)f2bf(b) << 16);
}
__device__ __forceinline__ float bfu_lo(unsigned u) {
  return __builtin_bit_cast(float, u << 16);
}
__device__ __forceinline__ float bfu_hi(unsigned u) {
  return __builtin_bit_cast(float, u & 0xFFFF0000u);
}

// ---------------- prep: zero bcnt + convert/transpose weights (3 blocks) ----------------
__global__ void k_prep(int* __restrict__ bcnt, const float* __restrict__ W1,
                       const float* __restrict__ W2, unsigned short* __restrict__ Wt1,
                       unsigned short* __restrict__ Wt2) {
  const int t = threadIdx.x;
  if (blockIdx.x == 0) {
    bcnt[t] = 0;
  } else if (blockIdx.x == 1) {
    for (int j = 0; j < 64; ++j) {
      int lin = j * 256 + t;
      int k = lin >> 6, c = lin & 63;
      Wt1[c * 256 + k] = f2bf(W1[lin]);
    }
  } else {
    for (int j = 0; j < 16; ++j) {
      int lin = j * 256 + t;
      int k = lin >> 6, c = lin & 63;
      Wt2[c * 64 + k] = f2bf(W2[lin]);
    }
  }
}

// ---------------- kA: coarse bucket histogram ----------------
__global__ void k_bhist(const int* __restrict__ dst, int* __restrict__ bcnt) {
  __shared__ int h[NBKT];
  const int t = threadIdx.x;
  for (int i = t; i < NBKT; i += 256) h[i] = 0;
  __syncthreads();
  const int base = blockIdx.x * CHUNK;
#pragma unroll
  for (int i = 0; i < CHUNK / 256; ++i) {
    int e = base + i * 256 + t;
    if (e < N_EDGES) atomicAdd(&h[dst[e] >> 8], 1);
  }
  __syncthreads();
  for (int i = t; i < NBKT; i += 256)
    if (h[i]) atomicAdd(&bcnt[i], h[i]);
}

// ---------------- kB: scan bucket counts -> bptr, bcur ----------------
__global__ void k_bscan(const int* __restrict__ bcnt, int* __restrict__ bptr,
                        int* __restrict__ bcur) {
  __shared__ int s[256];
  const int t = threadIdx.x;
  s[t] = (t < NBKT) ? bcnt[t] : 0;
  __syncthreads();
  for (int d = 1; d < 256; d <<= 1) {
    int v = s[t];
    int a = (t >= d) ? s[t - d] : 0;
    __syncthreads();
    s[t] = v + a;
    __syncthreads();
  }
  if (t < NBKT) {
    int ex = (t == 0) ? 0 : s[t - 1];
    bptr[t] = ex;
    bcur[t] = ex;
  } else if (t == NBKT) {
    bptr[NBKT] = N_EDGES;
  }
}

// ---------------- kC: multisplit into bucket regions (packed u32) ----------------
__global__ void k_split(const int* __restrict__ src, const int* __restrict__ dst,
                        int* __restrict__ bcur, unsigned* __restrict__ ebuf) {
  __shared__ int cnt[NBKT];
  __shared__ int cur[NBKT];
  const int t = threadIdx.x;
  for (int i = t; i < NBKT; i += 256) cnt[i] = 0;
  __syncthreads();
  const int base = blockIdx.x * CHUNK;
#pragma unroll
  for (int i = 0; i < CHUNK / 256; ++i) {
    int e = base + i * 256 + t;
    if (e < N_EDGES) atomicAdd(&cnt[dst[e] >> 8], 1);
  }
  __syncthreads();
  for (int i = t; i < NBKT; i += 256) {
    int c = cnt[i];
    cur[i] = c ? atomicAdd(&bcur[i], c) : 0;
  }
  __syncthreads();
#pragma unroll
  for (int i = 0; i < CHUNK / 256; ++i) {
    int e = base + i * 256 + t;
    if (e < N_EDGES) {
      int d = dst[e];
      int p = atomicAdd(&cur[d >> 8], 1);
      ebuf[p] = ((unsigned)src[e] << 8) | (unsigned)(d & 255);
    }
  }
}

// ---------------- kD: per-bucket fine CSR ----------------
__global__ void k_bucket(const unsigned* __restrict__ ebuf, const int* __restrict__ bptr,
                         int* __restrict__ rowptr, int* __restrict__ colidx,
                         float* __restrict__ dinv) {
  __shared__ int cnt[BKT];
  __shared__ int off[BKT];
  const int b = blockIdx.x, t = threadIdx.x;
  const int beg = bptr[b], end = bptr[b + 1];
  cnt[t] = 0;
  __syncthreads();
  for (int i = beg + t; i < end; i += 256) atomicAdd(&cnt[ebuf[i] & 255], 1);
  __syncthreads();
  off[t] = cnt[t];
  __syncthreads();
  for (int d = 1; d < 256; d <<= 1) {
    int v = off[t];
    int a = (t >= d) ? off[t - d] : 0;
    __syncthreads();
    off[t] = v + a;
    __syncthreads();
  }
  const int node = b * BKT + t;
  const int ex = beg + off[t] - cnt[t];
  if (node < N_NODES) {
    rowptr[node] = ex;
    dinv[node] = rsqrtf((float)(cnt[t] + 1));
    if (node == N_NODES - 1) rowptr[N_NODES] = N_EDGES;
  }
  __syncthreads();
  off[t] = ex;
  __syncthreads();
  for (int i = beg + t; i < end; i += 256) {
    unsigned p = ebuf[i];
    int pos = atomicAdd(&off[p & 255], 1);
    colidx[pos] = (int)(p >> 8);
  }
}

// ---------------- LDS-free MFMA GEMM ----------------
// out_bf[r][c] = bf16( dinv[r] * sum_k X[r][k] * W[k][c] ), 64 cols.
// 4 waves/block, each wave owns 16 rows; A/B frags use the same lane->k
// bijection (k = k0 + (lane>>4)*8 + i); C/D: col=lane&15, row=(lane>>4)*4+reg.
template <int K, bool XF32>
__global__ __launch_bounds__(256) void k_gemm(const void* __restrict__ Xv,
                                              const unsigned short* __restrict__ Wtg,
                                              const float* __restrict__ dinv,
                                              unsigned short* __restrict__ out) {
  const int t = threadIdx.x, lane = t & 63, wv = t >> 6;
  const int row0 = blockIdx.x * 64;
  int r = row0 + wv * 16 + (lane & 15);
  if (r > N_NODES - 1) r = N_NODES - 1;  // clamp (stores guarded)
  const int kh = (lane >> 4) * 8;

  f32x4 acc[4] = {};
#pragma unroll
  for (int k0 = 0; k0 < K; k0 += 32) {
    short8v a;
    if (XF32) {
      const float* X = (const float*)Xv + (size_t)r * K + k0 + kh;
      const float4 x0 = *reinterpret_cast<const float4*>(X);
      const float4 x1 = *reinterpret_cast<const float4*>(X + 4);
      uint4v p;
      p.x = pack2(x0.x, x0.y); p.y = pack2(x0.z, x0.w);
      p.z = pack2(x1.x, x1.y); p.w = pack2(x1.z, x1.w);
      a = __builtin_bit_cast(short8v, p);
    } else {
      a = *reinterpret_cast<const short8v*>(
          (const unsigned short*)Xv + (size_t)r * 64 + k0 + kh);
    }
#pragma unroll
    for (int n = 0; n < 4; ++n) {
      short8v b = *reinterpret_cast<const short8v*>(
          Wtg + (size_t)(n * 16 + (lane & 15)) * K + k0 + kh);
      acc[n] = __builtin_amdgcn_mfma_f32_16x16x32_bf16(a, b, acc[n], 0, 0, 0);
    }
  }

  const int r0 = row0 + wv * 16;
#pragma unroll
  for (int j = 0; j < 4; ++j) {
    int rr = r0 + (lane >> 4) * 4 + j;
    if (rr < N_NODES) {
      float s = dinv[rr];
#pragma unroll
      for (int n = 0; n < 4; ++n)
        out[(size_t)rr * 64 + n * 16 + (lane & 15)] = f2bf(acc[n][j] * s);
    }
  }
}

// ---------------- 4-nodes-per-wave CSR gather-aggregate ----------------
// lane = q*16 + l: quarter q handles node v=base+q, lane covers feats f0..f0+3.
// One uint2 (8B) load per lane => one VMEM instruction gathers 4 nodes' rows.
template <bool FINAL>
__global__ __launch_bounds__(256) void k_agg4(const unsigned short* __restrict__ h,
                                              const int* __restrict__ rowptr,
                                              const int* __restrict__ col,
                                              const float* __restrict__ dinv,
                                              const float* __restrict__ bias,
                                              const float* __restrict__ Wc,
                                              const float* __restrict__ bc,
                                              void* __restrict__ outv) {
  const int t = threadIdx.x, lane = t & 63;
  const int q = lane >> 4, f0 = (lane & 15) * 4;
  const int v = (blockIdx.x << 4) + ((t >> 6) << 2) + q;  // 16 nodes/block, exact

  int e = rowptr[v];
  const int end = rowptr[v + 1];

  uint2 sw = *reinterpret_cast<const uint2*>(&h[(size_t)v * 64 + f0]);
  float acc0 = bfu_lo(sw.x), acc1 = bfu_hi(sw.x);
  float acc2 = bfu_lo(sw.y), acc3 = bfu_hi(sw.y);

  for (; e + 4 <= end; e += 4) {
    int c0 = col[e], c1 = col[e + 1], c2 = col[e + 2], c3 = col[e + 3];
    uint2 w0 = *reinterpret_cast<const uint2*>(&h[(size_t)c0 * 64 + f0]);
    uint2 w1 = *reinterpret_cast<const uint2*>(&h[(size_t)c1 * 64 + f0]);
    uint2 w2 = *reinterpret_cast<const uint2*>(&h[(size_t)c2 * 64 + f0]);
    uint2 w3 = *reinterpret_cast<const uint2*>(&h[(size_t)c3 * 64 + f0]);
    acc0 += (bfu_lo(w0.x) + bfu_lo(w1.x)) + (bfu_lo(w2.x) + bfu_lo(w3.x));
    acc1 += (bfu_hi(w0.x) + bfu_hi(w1.x)) + (bfu_hi(w2.x) + bfu_hi(w3.x));
    acc2 += (bfu_lo(w0.y) + bfu_lo(w1.y)) + (bfu_lo(w2.y) + bfu_lo(w3.y));
    acc3 += (bfu_hi(w0.y) + bfu_hi(w1.y)) + (bfu_hi(w2.y) + bfu_hi(w3.y));
  }
  for (; e < end; ++e) {
    uint2 w0 = *reinterpret_cast<const uint2*>(&h[(size_t)col[e] * 64 + f0]);
    acc0 += bfu_lo(w0.x); acc1 += bfu_hi(w0.x);
    acc2 += bfu_lo(w0.y); acc3 += bfu_hi(w0.y);
  }

  const float s = dinv[v];
  const float4 b4 = *reinterpret_cast<const float4*>(&bias[f0]);
  float v0 = fmaxf(fmaf(s, acc0, b4.x), 0.0f);
  float v1 = fmaxf(fmaf(s, acc1, b4.y), 0.0f);
  float v2 = fmaxf(fmaf(s, acc2, b4.z), 0.0f);
  float v3 = fmaxf(fmaf(s, acc3, b4.w), 0.0f);

  if (!FINAL) {
    uint2 o;
    o.x = pack2(v0, v1);
    o.y = pack2(v2, v3);
    *reinterpret_cast<uint2*>(&((unsigned short*)outv)[(size_t)v * 64 + f0]) = o;
  } else {
    const float4 w4 = *reinterpret_cast<const float4*>(&Wc[f0]);
    float p = v0 * w4.x + v1 * w4.y + v2 * w4.z + v3 * w4.w;
    p += __shfl_xor(p, 1);
    p += __shfl_xor(p, 2);
    p += __shfl_xor(p, 4);
    p += __shfl_xor(p, 8);
    if ((lane & 15) == 0) ((float*)outv)[v] = 1.0f / (1.0f + expf(-(p + bc[0])));
  }
}

extern "C" void kernel_launch(void* const* d_in, const int* in_sizes, int n_in,
                              void* d_out, int out_size, void* d_ws, size_t ws_size,
                              hipStream_t stream) {
  const float* x  = (const float*)d_in[0];
  const int*   ei = (const int*)d_in[1];
  const float* W1 = (const float*)d_in[2];
  const float* b1 = (const float*)d_in[3];
  const float* W2 = (const float*)d_in[4];
  const float* b2 = (const float*)d_in[5];
  const float* Wc = (const float*)d_in[6];
  const float* bc = (const float*)d_in[7];
  float* out = (float*)d_out;

  const int* src = ei;
  const int* dst = ei + N_EDGES;

  // workspace layout (u32 units)
  unsigned* w = (unsigned*)d_ws;
  int*   bcnt   = (int*)(w + 0);            // 256
  int*   bptr   = (int*)(w + 256);          // 512
  int*   bcur   = (int*)(w + 768);          // 256
  int*   rowptr = (int*)(w + 1024);         // 50432
  int*   colidx = (int*)(w + 51456);        // 800000
  unsigned* ebuf = w + 851456;              // 800000
  float* dinv   = (float*)(w + 1651456);    // 50176
  unsigned short* Wt1g = (unsigned short*)(w + 1701632);  // 16384 ush
  unsigned short* Wt2g = (unsigned short*)(w + 1709824);  // 4096 ush
  unsigned short* A_bf = (unsigned short*)(w + 1711872);  // 3.2M ush
  unsigned short* B_bf = (unsigned short*)(w + 3311872);  // 3.2M ush

  // prep + CSR build
  k_prep<<<3, 256, 0, stream>>>(bcnt, W1, W2, Wt1g, Wt2g);
  k_bhist<<<NCH, 256, 0, stream>>>(dst, bcnt);
  k_bscan<<<1, 256, 0, stream>>>(bcnt, bptr, bcur);
  k_split<<<NCH, 256, 0, stream>>>(src, dst, bcur, ebuf);
  k_bucket<<<NBKT, 256, 0, stream>>>(ebuf, bptr, rowptr, colidx, dinv);

  const int NGB = (N_NODES + 63) / 64;   // 782
  const int NAB = N_NODES / 16;          // 3125
  // layer 1
  k_gemm<IN_DIM, true><<<NGB, 256, 0, stream>>>(x, Wt1g, dinv, A_bf);
  k_agg4<false><<<NAB, 256, 0, stream>>>(A_bf, rowptr, colidx, dinv, b1,
                                         nullptr, nullptr, B_bf);
  // layer 2
  k_gemm<HID, false><<<NGB, 256, 0, stream>>>(B_bf, Wt2g, dinv, A_bf);
  k_agg4<true><<<NAB, 256, 0, stream>>>(A_bf, rowptr, colidx, dinv, b2,
                                        Wc, bc, out);
}

// Round 7
// 111.522 us; speedup vs baseline: 4.2775x; 1.1583x over previous
//
#include <hip/hip_runtime.h>
#include <math.h>

#define N_NODES 50000
#define N_EDGES 800000
#define IN_DIM 256
#define HID 64
#define BKT 256
#define NBKT ((N_NODES + BKT - 1) / BKT)          // 196
#define CAP 8192                                  // ebuf slots per bucket (max real ~4400)
#define CHUNK 4096
#define NCH ((N_EDGES + CHUNK - 1) / CHUNK)       // 196

typedef short short8v __attribute__((ext_vector_type(8)));
typedef float f32x4 __attribute__((ext_vector_type(4)));
typedef unsigned uint4v __attribute__((ext_vector_type(4)));

__device__ __forceinline__ unsigned short f2bf(float f) {
  unsigned u = __builtin_bit_cast(unsigned, f);
  u += 0x7FFFu + ((u >> 16) & 1u);  // RNE
  return (unsigned short)(u >> 16);
}
__device__ __forceinline__ unsigned pack2(float a, float b) {
  return (unsigned)f2bf(a) | ((unsigned)f2bf(b) << 16);
}
__device__ __forceinline__ float bfu_lo(unsigned u) {
  return __builtin_bit_cast(float, u << 16);
}
__device__ __forceinline__ float bfu_hi(unsigned u) {
  return __builtin_bit_cast(float, u & 0xFFFF0000u);
}

// ---------------- prep: zero bcur + convert/transpose weights ----------------
__global__ void k_prep(int* __restrict__ bcur, const float* __restrict__ W1,
                       const float* __restrict__ W2, unsigned short* __restrict__ Wt1,
                       unsigned short* __restrict__ Wt2) {
  const int t = threadIdx.x;
  if (blockIdx.x == 0) {
    bcur[t] = 0;
  } else if (blockIdx.x == 1) {
    for (int j = 0; j < 64; ++j) {
      int lin = j * 256 + t;
      int k = lin >> 6, c = lin & 63;
      Wt1[c * 256 + k] = f2bf(W1[lin]);
    }
  } else {
    for (int j = 0; j < 16; ++j) {
      int lin = j * 256 + t;
      int k = lin >> 6, c = lin & 63;
      Wt2[c * 64 + k] = f2bf(W2[lin]);
    }
  }
}

// ---------------- split: edges -> padded bucket regions (packed u32) ----------------
__global__ void k_split(const int* __restrict__ src, const int* __restrict__ dst,
                        int* __restrict__ bcur, unsigned* __restrict__ ebuf) {
  __shared__ int cnt[NBKT];
  __shared__ int cur[NBKT];
  const int t = threadIdx.x;
  for (int i = t; i < NBKT; i += 256) cnt[i] = 0;
  __syncthreads();
  const int base = blockIdx.x * CHUNK;
#pragma unroll
  for (int i = 0; i < CHUNK / 256; ++i) {
    int e = base + i * 256 + t;
    if (e < N_EDGES) atomicAdd(&cnt[dst[e] >> 8], 1);
  }
  __syncthreads();
  for (int i = t; i < NBKT; i += 256) {
    int c = cnt[i];
    cur[i] = c ? (i * CAP + atomicAdd(&bcur[i], c)) : 0;
  }
  __syncthreads();
#pragma unroll
  for (int i = 0; i < CHUNK / 256; ++i) {
    int e = base + i * 256 + t;
    if (e < N_EDGES) {
      int d = dst[e];
      int p = atomicAdd(&cur[d >> 8], 1);
      ebuf[p] = ((unsigned)src[e] << 8) | (unsigned)(d & 255);
    }
  }
}

// ---------------- bucket: per-bucket fine CSR (rowptr, colidx, dinv) ----------------
__global__ void k_bucket(const unsigned* __restrict__ ebuf, const int* __restrict__ bcur,
                         int* __restrict__ rowptr, int* __restrict__ colidx,
                         float* __restrict__ dinv) {
  __shared__ int sA[256];
  __shared__ int sB[256];
  const int b = blockIdx.x, t = threadIdx.x;

  // redundant in-block exclusive scan of bucket counts -> compact colidx base
  sA[t] = (t < NBKT) ? bcur[t] : 0;
  __syncthreads();
  for (int d = 1; d < 256; d <<= 1) {
    int v = sA[t];
    int a = (t >= d) ? sA[t - d] : 0;
    __syncthreads();
    sA[t] = v + a;
    __syncthreads();
  }
  const int prefix = (b == 0) ? 0 : sA[b - 1];
  const int cntb = bcur[b];
  const int sbeg = b * CAP, send = sbeg + cntb;
  __syncthreads();

  // per-node histogram within bucket
  sA[t] = 0;
  __syncthreads();
  for (int i = sbeg + t; i < send; i += 256) atomicAdd(&sA[ebuf[i] & 255], 1);
  __syncthreads();
  const int myc = sA[t];
  sB[t] = myc;
  __syncthreads();
  for (int d = 1; d < 256; d <<= 1) {
    int v = sB[t];
    int a = (t >= d) ? sB[t - d] : 0;
    __syncthreads();
    sB[t] = v + a;
    __syncthreads();
  }
  const int node = b * BKT + t;
  const int ex = prefix + sB[t] - myc;  // exclusive within bucket + global base
  if (node < N_NODES) {
    rowptr[node] = ex;
    dinv[node] = rsqrtf((float)(myc + 1));
    if (node == N_NODES - 1) rowptr[N_NODES] = N_EDGES;
  }
  __syncthreads();
  sB[t] = ex;  // per-node cursor
  __syncthreads();
  for (int i = sbeg + t; i < send; i += 256) {
    unsigned p = ebuf[i];
    int pos = atomicAdd(&sB[p & 255], 1);
    colidx[pos] = (int)(p >> 8);
  }
}

// ---------------- LDS-free MFMA GEMM (layer 1) ----------------
template <int K, bool XF32>
__global__ __launch_bounds__(256) void k_gemm(const void* __restrict__ Xv,
                                              const unsigned short* __restrict__ Wtg,
                                              const float* __restrict__ dinv,
                                              unsigned short* __restrict__ out) {
  const int t = threadIdx.x, lane = t & 63, wv = t >> 6;
  const int row0 = blockIdx.x * 64;
  int r = row0 + wv * 16 + (lane & 15);
  if (r > N_NODES - 1) r = N_NODES - 1;  // clamp (stores guarded)
  const int kh = (lane >> 4) * 8;

  f32x4 acc[4] = {};
#pragma unroll
  for (int k0 = 0; k0 < K; k0 += 32) {
    short8v a;
    if (XF32) {
      const float* X = (const float*)Xv + (size_t)r * K + k0 + kh;
      const float4 x0 = *reinterpret_cast<const float4*>(X);
      const float4 x1 = *reinterpret_cast<const float4*>(X + 4);
      uint4v p;
      p.x = pack2(x0.x, x0.y); p.y = pack2(x0.z, x0.w);
      p.z = pack2(x1.x, x1.y); p.w = pack2(x1.z, x1.w);
      a = __builtin_bit_cast(short8v, p);
    } else {
      a = *reinterpret_cast<const short8v*>(
          (const unsigned short*)Xv + (size_t)r * 64 + k0 + kh);
    }
#pragma unroll
    for (int n = 0; n < 4; ++n) {
      short8v b = *reinterpret_cast<const short8v*>(
          Wtg + (size_t)(n * 16 + (lane & 15)) * K + k0 + kh);
      acc[n] = __builtin_amdgcn_mfma_f32_16x16x32_bf16(a, b, acc[n], 0, 0, 0);
    }
  }

  const int r0 = row0 + wv * 16;
#pragma unroll
  for (int j = 0; j < 4; ++j) {
    int rr = r0 + (lane >> 4) * 4 + j;
    if (rr < N_NODES) {
      float s = dinv[rr];
#pragma unroll
      for (int n = 0; n < 4; ++n)
        out[(size_t)rr * 64 + n * 16 + (lane & 15)] = f2bf(acc[n][j] * s);
    }
  }
}

// ---------------- gather body (shared by both agg kernels) ----------------
#define GATHER_ACC(hbuf)                                                           \
  int e = rowptr[v];                                                               \
  const int end = rowptr[v + 1];                                                   \
  uint2 sw = *reinterpret_cast<const uint2*>(&hbuf[(size_t)v * 64 + f0]);          \
  float acc0 = bfu_lo(sw.x), acc1 = bfu_hi(sw.x);                                  \
  float acc2 = bfu_lo(sw.y), acc3 = bfu_hi(sw.y);                                  \
  for (; e + 8 <= end; e += 8) {                                                   \
    int c0 = col[e], c1 = col[e + 1], c2 = col[e + 2], c3 = col[e + 3];            \
    int c4 = col[e + 4], c5 = col[e + 5], c6 = col[e + 6], c7 = col[e + 7];        \
    uint2 w0 = *reinterpret_cast<const uint2*>(&hbuf[(size_t)c0 * 64 + f0]);       \
    uint2 w1 = *reinterpret_cast<const uint2*>(&hbuf[(size_t)c1 * 64 + f0]);       \
    uint2 w2 = *reinterpret_cast<const uint2*>(&hbuf[(size_t)c2 * 64 + f0]);       \
    uint2 w3 = *reinterpret_cast<const uint2*>(&hbuf[(size_t)c3 * 64 + f0]);       \
    uint2 w4 = *reinterpret_cast<const uint2*>(&hbuf[(size_t)c4 * 64 + f0]);       \
    uint2 w5 = *reinterpret_cast<const uint2*>(&hbuf[(size_t)c5 * 64 + f0]);       \
    uint2 w6 = *reinterpret_cast<const uint2*>(&hbuf[(size_t)c6 * 64 + f0]);       \
    uint2 w7 = *reinterpret_cast<const uint2*>(&hbuf[(size_t)c7 * 64 + f0]);       \
    acc0 += ((bfu_lo(w0.x) + bfu_lo(w1.x)) + (bfu_lo(w2.x) + bfu_lo(w3.x))) +      \
            ((bfu_lo(w4.x) + bfu_lo(w5.x)) + (bfu_lo(w6.x) + bfu_lo(w7.x)));       \
    acc1 += ((bfu_hi(w0.x) + bfu_hi(w1.x)) + (bfu_hi(w2.x) + bfu_hi(w3.x))) +      \
            ((bfu_hi(w4.x) + bfu_hi(w5.x)) + (bfu_hi(w6.x) + bfu_hi(w7.x)));       \
    acc2 += ((bfu_lo(w0.y) + bfu_lo(w1.y)) + (bfu_lo(w2.y) + bfu_lo(w3.y))) +      \
            ((bfu_lo(w4.y) + bfu_lo(w5.y)) + (bfu_lo(w6.y) + bfu_lo(w7.y)));       \
    acc3 += ((bfu_hi(w0.y) + bfu_hi(w1.y)) + (bfu_hi(w2.y) + bfu_hi(w3.y))) +      \
            ((bfu_hi(w4.y) + bfu_hi(w5.y)) + (bfu_hi(w6.y) + bfu_hi(w7.y)));       \
  }                                                                                \
  for (; e + 4 <= end; e += 4) {                                                   \
    int c0 = col[e], c1 = col[e + 1], c2 = col[e + 2], c3 = col[e + 3];            \
    uint2 w0 = *reinterpret_cast<const uint2*>(&hbuf[(size_t)c0 * 64 + f0]);       \
    uint2 w1 = *reinterpret_cast<const uint2*>(&hbuf[(size_t)c1 * 64 + f0]);       \
    uint2 w2 = *reinterpret_cast<const uint2*>(&hbuf[(size_t)c2 * 64 + f0]);       \
    uint2 w3 = *reinterpret_cast<const uint2*>(&hbuf[(size_t)c3 * 64 + f0]);       \
    acc0 += (bfu_lo(w0.x) + bfu_lo(w1.x)) + (bfu_lo(w2.x) + bfu_lo(w3.x));         \
    acc1 += (bfu_hi(w0.x) + bfu_hi(w1.x)) + (bfu_hi(w2.x) + bfu_hi(w3.x));         \
    acc2 += (bfu_lo(w0.y) + bfu_lo(w1.y)) + (bfu_lo(w2.y) + bfu_lo(w3.y));         \
    acc3 += (bfu_hi(w0.y) + bfu_hi(w1.y)) + (bfu_hi(w2.y) + bfu_hi(w3.y));         \
  }                                                                                \
  for (; e < end; ++e) {                                                           \
    uint2 w0 = *reinterpret_cast<const uint2*>(&hbuf[(size_t)col[e] * 64 + f0]);   \
    acc0 += bfu_lo(w0.x); acc1 += bfu_hi(w0.x);                                    \
    acc2 += bfu_lo(w0.y); acc3 += bfu_hi(w0.y);                                    \
  }

// ---------------- agg1 + GEMM2 fused ----------------
// Phase 1 (gather): 16 nodes/block, quarter q of wave wv owns node v, 16 lanes
// cover feats. Phase 2: block's 16x64 relu'd h1 tile -> LDS -> 16x64x64 MFMA
// with W2t -> h2s (dinv-scaled, bf16) written once.
__global__ __launch_bounds__(256) void k_agg_gemm(
    const unsigned short* __restrict__ h, const int* __restrict__ rowptr,
    const int* __restrict__ col, const float* __restrict__ dinv,
    const float* __restrict__ bias, const unsigned short* __restrict__ Wt2g,
    unsigned short* __restrict__ out) {
  const int t = threadIdx.x, lane = t & 63, wv = t >> 6;
  const int q = lane >> 4, f0 = (lane & 15) * 4;
  const int vbase = blockIdx.x << 4;
  const int v = vbase + (wv << 2) + q;

  GATHER_ACC(h)

  const float s = dinv[v];
  const float4 b4 = *reinterpret_cast<const float4*>(&bias[f0]);
  float v0 = fmaxf(fmaf(s, acc0, b4.x), 0.0f);
  float v1 = fmaxf(fmaf(s, acc1, b4.y), 0.0f);
  float v2 = fmaxf(fmaf(s, acc2, b4.z), 0.0f);
  float v3 = fmaxf(fmaf(s, acc3, b4.w), 0.0f);

  __shared__ unsigned short h1s[16][72];  // +8 pad: 144B row stride, 2-way max
  {
    uint2 o;
    o.x = pack2(v0, v1);
    o.y = pack2(v2, v3);
    *reinterpret_cast<uint2*>(&h1s[(wv << 2) + q][f0]) = o;
  }
  __syncthreads();

  // GEMM2: rows = 16 nodes, wave wv owns cols [wv*16, wv*16+16), K = 64
  const int kh = (lane >> 4) * 8;
  f32x4 acc = {};
#pragma unroll
  for (int k0 = 0; k0 < 64; k0 += 32) {
    short8v a = *reinterpret_cast<const short8v*>(&h1s[lane & 15][k0 + kh]);
    short8v b = *reinterpret_cast<const short8v*>(
        Wt2g + (size_t)(wv * 16 + (lane & 15)) * 64 + k0 + kh);
    acc = __builtin_amdgcn_mfma_f32_16x16x32_bf16(a, b, acc, 0, 0, 0);
  }
#pragma unroll
  for (int j = 0; j < 4; ++j) {
    int row = (lane >> 4) * 4 + j;
    int vg = vbase + row;
    out[(size_t)vg * 64 + wv * 16 + (lane & 15)] = f2bf(acc[j] * dinv[vg]);
  }
}

// ---------------- agg2 + classifier fused ----------------
__global__ __launch_bounds__(256) void k_agg_fin(
    const unsigned short* __restrict__ h, const int* __restrict__ rowptr,
    const int* __restrict__ col, const float* __restrict__ dinv,
    const float* __restrict__ bias, const float* __restrict__ Wc,
    const float* __restrict__ bc, float* __restrict__ out) {
  const int t = threadIdx.x, lane = t & 63;
  const int q = lane >> 4, f0 = (lane & 15) * 4;
  const int v = (blockIdx.x << 4) + ((t >> 6) << 2) + q;

  GATHER_ACC(h)

  const float s = dinv[v];
  const float4 b4 = *reinterpret_cast<const float4*>(&bias[f0]);
  float v0 = fmaxf(fmaf(s, acc0, b4.x), 0.0f);
  float v1 = fmaxf(fmaf(s, acc1, b4.y), 0.0f);
  float v2 = fmaxf(fmaf(s, acc2, b4.z), 0.0f);
  float v3 = fmaxf(fmaf(s, acc3, b4.w), 0.0f);

  const float4 w4 = *reinterpret_cast<const float4*>(&Wc[f0]);
  float p = v0 * w4.x + v1 * w4.y + v2 * w4.z + v3 * w4.w;
  p += __shfl_xor(p, 1);
  p += __shfl_xor(p, 2);
  p += __shfl_xor(p, 4);
  p += __shfl_xor(p, 8);
  if ((lane & 15) == 0) out[v] = 1.0f / (1.0f + expf(-(p + bc[0])));
}

extern "C" void kernel_launch(void* const* d_in, const int* in_sizes, int n_in,
                              void* d_out, int out_size, void* d_ws, size_t ws_size,
                              hipStream_t stream) {
  const float* x  = (const float*)d_in[0];
  const int*   ei = (const int*)d_in[1];
  const float* W1 = (const float*)d_in[2];
  const float* b1 = (const float*)d_in[3];
  const float* W2 = (const float*)d_in[4];
  const float* b2 = (const float*)d_in[5];
  const float* Wc = (const float*)d_in[6];
  const float* bc = (const float*)d_in[7];
  float* out = (float*)d_out;

  const int* src = ei;
  const int* dst = ei + N_EDGES;

  // workspace layout (u32 units)
  unsigned* w = (unsigned*)d_ws;
  int*   bcur   = (int*)(w + 0);            // 256
  int*   rowptr = (int*)(w + 256);          // 50432 (needs 50001)
  int*   colidx = (int*)(w + 50688);        // 800000
  unsigned* ebuf = w + 850688;              // 196*8192 = 1605632
  float* dinv   = (float*)(w + 2456320);    // 50176
  unsigned short* Wt1g = (unsigned short*)(w + 2506496);  // 16384 ush
  unsigned short* Wt2g = (unsigned short*)(w + 2514688);  // 4096 ush
  unsigned short* A_bf = (unsigned short*)(w + 2516736);  // 3.2M ush
  unsigned short* B_bf = (unsigned short*)(w + 4116736);  // 3.2M ush

  // prep + CSR build (3 kernels)
  k_prep<<<3, 256, 0, stream>>>(bcur, W1, W2, Wt1g, Wt2g);
  k_split<<<NCH, 256, 0, stream>>>(src, dst, bcur, ebuf);
  k_bucket<<<NBKT, 256, 0, stream>>>(ebuf, bcur, rowptr, colidx, dinv);

  const int NGB = (N_NODES + 63) / 64;   // 782
  const int NAB = N_NODES / 16;          // 3125
  // layer 1 GEMM -> h1s'
  k_gemm<IN_DIM, true><<<NGB, 256, 0, stream>>>(x, Wt1g, dinv, A_bf);
  // agg1 + layer 2 GEMM fused -> h2s'
  k_agg_gemm<<<NAB, 256, 0, stream>>>(A_bf, rowptr, colidx, dinv, b1, Wt2g, B_bf);
  // agg2 + classifier fused -> out
  k_agg_fin<<<NAB, 256, 0, stream>>>(B_bf, rowptr, colidx, dinv, b2, Wc, bc, out);
}

// Round 8
// 104.690 us; speedup vs baseline: 4.5566x; 1.0653x over previous
//
#include <hip/hip_runtime.h>
#include <math.h>

#define N_NODES 50000
#define N_EDGES 800000
#define IN_DIM 256
#define HID 64
#define BKT 256
#define NBKT ((N_NODES + BKT - 1) / BKT)          // 196
#define CAP 8192                                  // ebuf slots per bucket (max real ~4400)
#define CHUNK 4096
#define NCH ((N_EDGES + CHUNK - 1) / CHUNK)       // 196
#define NGB ((N_NODES + 63) / 64)                 // 782

typedef short short8v __attribute__((ext_vector_type(8)));
typedef float f32x4 __attribute__((ext_vector_type(4)));
typedef unsigned uint4v __attribute__((ext_vector_type(4)));

__device__ __forceinline__ unsigned short f2bf(float f) {
  unsigned u = __builtin_bit_cast(unsigned, f);
  u += 0x7FFFu + ((u >> 16) & 1u);  // RNE
  return (unsigned short)(u >> 16);
}
__device__ __forceinline__ unsigned pack2(float a, float b) {
  return (unsigned)f2bf(a) | ((unsigned)f2bf(b) << 16);
}
__device__ __forceinline__ float bfu_lo(unsigned u) {
  return __builtin_bit_cast(float, u << 16);
}
__device__ __forceinline__ float bfu_hi(unsigned u) {
  return __builtin_bit_cast(float, u & 0xFFFF0000u);
}

// ---------------- prep: zero bcur + convert/transpose weights ----------------
__global__ void k_prep(int* __restrict__ bcur, const float* __restrict__ W1,
                       const float* __restrict__ W2, unsigned short* __restrict__ Wt1,
                       unsigned short* __restrict__ Wt2) {
  const int t = threadIdx.x;
  if (blockIdx.x == 0) {
    bcur[t] = 0;
  } else if (blockIdx.x == 1) {
    for (int j = 0; j < 64; ++j) {
      int lin = j * 256 + t;
      int k = lin >> 6, c = lin & 63;
      Wt1[c * 256 + k] = f2bf(W1[lin]);
    }
  } else {
    for (int j = 0; j < 16; ++j) {
      int lin = j * 256 + t;
      int k = lin >> 6, c = lin & 63;
      Wt2[c * 64 + k] = f2bf(W2[lin]);
    }
  }
}

// ---------------- fused: GEMM1 (blocks 0..NGB) || split (blocks NGB..NGB+NCH) ----------------
// GEMM1: outA[r][c] = bf16( sum_k X[r][k]*W1[k][c] )  -- UNSCALED (dinv applied per-edge later)
__global__ __launch_bounds__(256) void k_g1split(
    const float* __restrict__ X, const unsigned short* __restrict__ Wt1g,
    unsigned short* __restrict__ outA, const int* __restrict__ src,
    const int* __restrict__ dst, int* __restrict__ bcur, unsigned* __restrict__ ebuf) {
  const int t = threadIdx.x;
  if (blockIdx.x < NGB) {
    const int lane = t & 63, wv = t >> 6;
    const int row0 = blockIdx.x * 64;
    int r = row0 + wv * 16 + (lane & 15);
    if (r > N_NODES - 1) r = N_NODES - 1;  // clamp (stores guarded)
    const int kh = (lane >> 4) * 8;

    f32x4 acc[4] = {};
#pragma unroll
    for (int k0 = 0; k0 < IN_DIM; k0 += 32) {
      const float* Xp = X + (size_t)r * IN_DIM + k0 + kh;
      const float4 x0 = *reinterpret_cast<const float4*>(Xp);
      const float4 x1 = *reinterpret_cast<const float4*>(Xp + 4);
      uint4v p;
      p.x = pack2(x0.x, x0.y); p.y = pack2(x0.z, x0.w);
      p.z = pack2(x1.x, x1.y); p.w = pack2(x1.z, x1.w);
      short8v a = __builtin_bit_cast(short8v, p);
#pragma unroll
      for (int n = 0; n < 4; ++n) {
        short8v b = *reinterpret_cast<const short8v*>(
            Wt1g + (size_t)(n * 16 + (lane & 15)) * IN_DIM + k0 + kh);
        acc[n] = __builtin_amdgcn_mfma_f32_16x16x32_bf16(a, b, acc[n], 0, 0, 0);
      }
    }
    const int r0 = row0 + wv * 16;
#pragma unroll
    for (int j = 0; j < 4; ++j) {
      int rr = r0 + (lane >> 4) * 4 + j;
      if (rr < N_NODES) {
#pragma unroll
        for (int n = 0; n < 4; ++n)
          outA[(size_t)rr * 64 + n * 16 + (lane & 15)] = f2bf(acc[n][j]);
      }
    }
  } else {
    // ---- split: edges -> padded bucket regions (packed u32) ----
    __shared__ int cnt[NBKT];
    __shared__ int cur[NBKT];
    for (int i = t; i < NBKT; i += 256) cnt[i] = 0;
    __syncthreads();
    const int base = (blockIdx.x - NGB) * CHUNK;
#pragma unroll
    for (int i = 0; i < CHUNK / 256; ++i) {
      int e = base + i * 256 + t;
      if (e < N_EDGES) atomicAdd(&cnt[dst[e] >> 8], 1);
    }
    __syncthreads();
    for (int i = t; i < NBKT; i += 256) {
      int c = cnt[i];
      cur[i] = c ? (i * CAP + atomicAdd(&bcur[i], c)) : 0;
    }
    __syncthreads();
#pragma unroll
    for (int i = 0; i < CHUNK / 256; ++i) {
      int e = base + i * 256 + t;
      if (e < N_EDGES) {
        int d = dst[e];
        int p = atomicAdd(&cur[d >> 8], 1);
        ebuf[p] = ((unsigned)src[e] << 8) | (unsigned)(d & 255);
      }
    }
  }
}

// ---------------- bucket: per-bucket fine CSR (rowptr, colidx, dinv) ----------------
__global__ void k_bucket(const unsigned* __restrict__ ebuf, const int* __restrict__ bcur,
                         int* __restrict__ rowptr, int* __restrict__ colidx,
                         float* __restrict__ dinv) {
  __shared__ int sA[256];
  __shared__ int sB[256];
  const int b = blockIdx.x, t = threadIdx.x;

  sA[t] = (t < NBKT) ? bcur[t] : 0;
  __syncthreads();
  for (int d = 1; d < 256; d <<= 1) {
    int v = sA[t];
    int a = (t >= d) ? sA[t - d] : 0;
    __syncthreads();
    sA[t] = v + a;
    __syncthreads();
  }
  const int prefix = (b == 0) ? 0 : sA[b - 1];
  const int cntb = bcur[b];
  const int sbeg = b * CAP, send = sbeg + cntb;
  __syncthreads();

  sA[t] = 0;
  __syncthreads();
  for (int i = sbeg + t; i < send; i += 256) atomicAdd(&sA[ebuf[i] & 255], 1);
  __syncthreads();
  const int myc = sA[t];
  sB[t] = myc;
  __syncthreads();
  for (int d = 1; d < 256; d <<= 1) {
    int v = sB[t];
    int a = (t >= d) ? sB[t - d] : 0;
    __syncthreads();
    sB[t] = v + a;
    __syncthreads();
  }
  const int node = b * BKT + t;
  const int ex = prefix + sB[t] - myc;
  if (node < N_NODES) {
    rowptr[node] = ex;
    dinv[node] = rsqrtf((float)(myc + 1));
    if (node == N_NODES - 1) rowptr[N_NODES] = N_EDGES;
  }
  __syncthreads();
  sB[t] = ex;
  __syncthreads();
  for (int i = sbeg + t; i < send; i += 256) {
    unsigned p = ebuf[i];
    int pos = atomicAdd(&sB[p & 255], 1);
    colidx[pos] = (int)(p >> 8);
  }
}

// ---------------- edinv: dinvE[e] = dinv[colidx[e]] ----------------
__global__ __launch_bounds__(256) void k_edinv(const int* __restrict__ colidx,
                                               const float* __restrict__ dinv,
                                               float* __restrict__ dinvE) {
  int i = (blockIdx.x * 256 + threadIdx.x) * 4;
  if (i < N_EDGES) {
    int4 c = *reinterpret_cast<const int4*>(&colidx[i]);
    float4 o;
    o.x = dinv[c.x]; o.y = dinv[c.y]; o.z = dinv[c.z]; o.w = dinv[c.w];
    *reinterpret_cast<float4*>(&dinvE[i]) = o;
  }
}

// ---------------- agg1 (fma-scaled gather) + bias/relu + GEMM2 fused ----------------
// 8 lanes per node (uint4 = 8 feats each), 8 nodes/wave, 32 nodes/block.
__global__ __launch_bounds__(256) void k_agg_gemm(
    const unsigned short* __restrict__ h, const int* __restrict__ rowptr,
    const int* __restrict__ col, const float* __restrict__ dinv,
    const float* __restrict__ dinvE, const float* __restrict__ bias,
    const unsigned short* __restrict__ Wt2g, unsigned short* __restrict__ out) {
  const int t = threadIdx.x, lane = t & 63, wv = t >> 6;
  const int g = lane >> 3, f0 = (lane & 7) * 8;
  const int vbase = blockIdx.x * 32;
  const int v = vbase + wv * 8 + g;
  const int lrow = wv * 8 + g;

  __shared__ unsigned short h1s[32][72];  // pad: 144B stride -> 2-way max on MFMA reads

  if (v < N_NODES) {
    int e = rowptr[v];
    const int end = rowptr[v + 1];
    const float sv = dinv[v];

    uint4 sw = *reinterpret_cast<const uint4*>(&h[(size_t)v * 64 + f0]);
    float acc0 = sv * bfu_lo(sw.x), acc1 = sv * bfu_hi(sw.x);
    float acc2 = sv * bfu_lo(sw.y), acc3 = sv * bfu_hi(sw.y);
    float acc4 = sv * bfu_lo(sw.z), acc5 = sv * bfu_hi(sw.z);
    float acc6 = sv * bfu_lo(sw.w), acc7 = sv * bfu_hi(sw.w);

#define EDGE1(cc, dv)                                                         \
  {                                                                           \
    uint4 w = *reinterpret_cast<const uint4*>(&h[(size_t)(cc) * 64 + f0]);    \
    acc0 = fmaf(dv, bfu_lo(w.x), acc0); acc1 = fmaf(dv, bfu_hi(w.x), acc1);   \
    acc2 = fmaf(dv, bfu_lo(w.y), acc2); acc3 = fmaf(dv, bfu_hi(w.y), acc3);   \
    acc4 = fmaf(dv, bfu_lo(w.z), acc4); acc5 = fmaf(dv, bfu_hi(w.z), acc5);   \
    acc6 = fmaf(dv, bfu_lo(w.w), acc6); acc7 = fmaf(dv, bfu_hi(w.w), acc7);   \
  }
    // head: realign e to 4
    while (e < end && (e & 3)) { EDGE1(col[e], dinvE[e]); ++e; }
    // body: vectorized metadata (int4 col + float4 dinvE, broadcast per 8-lane group)
    for (; e + 4 <= end; e += 4) {
      int4 cc = *reinterpret_cast<const int4*>(&col[e]);
      float4 dd = *reinterpret_cast<const float4*>(&dinvE[e]);
      EDGE1(cc.x, dd.x);
      EDGE1(cc.y, dd.y);
      EDGE1(cc.z, dd.z);
      EDGE1(cc.w, dd.w);
    }
    // tail
    for (; e < end; ++e) { EDGE1(col[e], dinvE[e]); }
#undef EDGE1

    const float4 ba = *reinterpret_cast<const float4*>(&bias[f0]);
    const float4 bb = *reinterpret_cast<const float4*>(&bias[f0 + 4]);
    float v0 = fmaxf(fmaf(sv, acc0, ba.x), 0.0f);
    float v1 = fmaxf(fmaf(sv, acc1, ba.y), 0.0f);
    float v2 = fmaxf(fmaf(sv, acc2, ba.z), 0.0f);
    float v3 = fmaxf(fmaf(sv, acc3, ba.w), 0.0f);
    float v4 = fmaxf(fmaf(sv, acc4, bb.x), 0.0f);
    float v5 = fmaxf(fmaf(sv, acc5, bb.y), 0.0f);
    float v6 = fmaxf(fmaf(sv, acc6, bb.z), 0.0f);
    float v7 = fmaxf(fmaf(sv, acc7, bb.w), 0.0f);

    uint4 o;
    o.x = pack2(v0, v1); o.y = pack2(v2, v3);
    o.z = pack2(v4, v5); o.w = pack2(v6, v7);
    *reinterpret_cast<uint4*>(&h1s[lrow][f0]) = o;
  } else {
    uint4 z = {0, 0, 0, 0};
    *reinterpret_cast<uint4*>(&h1s[lrow][f0]) = z;
  }
  __syncthreads();

  // GEMM2: 32 nodes x 64 cols; wave wv owns cols [wv*16, wv*16+16); K=64.
  const int kh = (lane >> 4) * 8;
  f32x4 acc2r[2] = {};
#pragma unroll
  for (int rt = 0; rt < 2; ++rt) {
#pragma unroll
    for (int k0 = 0; k0 < 64; k0 += 32) {
      short8v a = *reinterpret_cast<const short8v*>(&h1s[rt * 16 + (lane & 15)][k0 + kh]);
      short8v b = *reinterpret_cast<const short8v*>(
          Wt2g + (size_t)(wv * 16 + (lane & 15)) * 64 + k0 + kh);
      acc2r[rt] = __builtin_amdgcn_mfma_f32_16x16x32_bf16(a, b, acc2r[rt], 0, 0, 0);
    }
  }
#pragma unroll
  for (int rt = 0; rt < 2; ++rt) {
#pragma unroll
    for (int j = 0; j < 4; ++j) {
      int vg = vbase + rt * 16 + (lane >> 4) * 4 + j;
      if (vg < N_NODES)
        out[(size_t)vg * 64 + wv * 16 + (lane & 15)] = f2bf(acc2r[rt][j] * dinv[vg]);
    }
  }
}

// ---------------- agg2 (pre-scaled h2s, plain adds) + classifier fused ----------------
__global__ __launch_bounds__(256) void k_agg_fin(
    const unsigned short* __restrict__ h, const int* __restrict__ rowptr,
    const int* __restrict__ col, const float* __restrict__ dinv,
    const float* __restrict__ bias, const float* __restrict__ Wc,
    const float* __restrict__ bc, float* __restrict__ out) {
  const int t = threadIdx.x, lane = t & 63;
  const int g = lane >> 3, f0 = (lane & 7) * 8;
  const int v = blockIdx.x * 32 + (t >> 6) * 8 + g;
  if (v >= N_NODES) return;

  int e = rowptr[v];
  const int end = rowptr[v + 1];

  uint4 sw = *reinterpret_cast<const uint4*>(&h[(size_t)v * 64 + f0]);
  float acc0 = bfu_lo(sw.x), acc1 = bfu_hi(sw.x);
  float acc2 = bfu_lo(sw.y), acc3 = bfu_hi(sw.y);
  float acc4 = bfu_lo(sw.z), acc5 = bfu_hi(sw.z);
  float acc6 = bfu_lo(sw.w), acc7 = bfu_hi(sw.w);

#define EDGE2(cc)                                                           \
  {                                                                         \
    uint4 w = *reinterpret_cast<const uint4*>(&h[(size_t)(cc) * 64 + f0]);  \
    acc0 += bfu_lo(w.x); acc1 += bfu_hi(w.x);                               \
    acc2 += bfu_lo(w.y); acc3 += bfu_hi(w.y);                               \
    acc4 += bfu_lo(w.z); acc5 += bfu_hi(w.z);                               \
    acc6 += bfu_lo(w.w); acc7 += bfu_hi(w.w);                               \
  }
  while (e < end && (e & 3)) { EDGE2(col[e]); ++e; }
  for (; e + 4 <= end; e += 4) {
    int4 cc = *reinterpret_cast<const int4*>(&col[e]);
    EDGE2(cc.x);
    EDGE2(cc.y);
    EDGE2(cc.z);
    EDGE2(cc.w);
  }
  for (; e < end; ++e) { EDGE2(col[e]); }
#undef EDGE2

  const float sv = dinv[v];
  const float4 ba = *reinterpret_cast<const float4*>(&bias[f0]);
  const float4 bb = *reinterpret_cast<const float4*>(&bias[f0 + 4]);
  const float4 wa = *reinterpret_cast<const float4*>(&Wc[f0]);
  const float4 wb = *reinterpret_cast<const float4*>(&Wc[f0 + 4]);
  float p = fmaxf(fmaf(sv, acc0, ba.x), 0.0f) * wa.x +
            fmaxf(fmaf(sv, acc1, ba.y), 0.0f) * wa.y +
            fmaxf(fmaf(sv, acc2, ba.z), 0.0f) * wa.z +
            fmaxf(fmaf(sv, acc3, ba.w), 0.0f) * wa.w +
            fmaxf(fmaf(sv, acc4, bb.x), 0.0f) * wb.x +
            fmaxf(fmaf(sv, acc5, bb.y), 0.0f) * wb.y +
            fmaxf(fmaf(sv, acc6, bb.z), 0.0f) * wb.z +
            fmaxf(fmaf(sv, acc7, bb.w), 0.0f) * wb.w;
  p += __shfl_xor(p, 1);
  p += __shfl_xor(p, 2);
  p += __shfl_xor(p, 4);
  if ((lane & 7) == 0) out[v] = 1.0f / (1.0f + expf(-(p + bc[0])));
}

extern "C" void kernel_launch(void* const* d_in, const int* in_sizes, int n_in,
                              void* d_out, int out_size, void* d_ws, size_t ws_size,
                              hipStream_t stream) {
  const float* x  = (const float*)d_in[0];
  const int*   ei = (const int*)d_in[1];
  const float* W1 = (const float*)d_in[2];
  const float* b1 = (const float*)d_in[3];
  const float* W2 = (const float*)d_in[4];
  const float* b2 = (const float*)d_in[5];
  const float* Wc = (const float*)d_in[6];
  const float* bc = (const float*)d_in[7];
  float* out = (float*)d_out;

  const int* src = ei;
  const int* dst = ei + N_EDGES;

  // workspace layout (u32 units)
  unsigned* w = (unsigned*)d_ws;
  int*   bcur   = (int*)(w + 0);            // 256
  int*   rowptr = (int*)(w + 256);          // 50432 (needs 50001)
  int*   colidx = (int*)(w + 50688);        // 800000
  unsigned* ebuf = w + 850688;              // 196*8192 = 1605632
  float* dinv   = (float*)(w + 2456320);    // 50176
  float* dinvE  = (float*)(w + 2506496);    // 800000
  unsigned short* Wt1g = (unsigned short*)(w + 3306496);  // 16384 ush
  unsigned short* Wt2g = (unsigned short*)(w + 3314688);  // 4096 ush
  unsigned short* A_bf = (unsigned short*)(w + 3316736);  // 3.2M ush
  unsigned short* B_bf = (unsigned short*)(w + 4916736);  // 3.2M ush

  k_prep<<<3, 256, 0, stream>>>(bcur, W1, W2, Wt1g, Wt2g);
  // GEMM1 (independent of CSR now) runs concurrently with split
  k_g1split<<<NGB + NCH, 256, 0, stream>>>(x, Wt1g, A_bf, src, dst, bcur, ebuf);
  k_bucket<<<NBKT, 256, 0, stream>>>(ebuf, bcur, rowptr, colidx, dinv);
  k_edinv<<<(N_EDGES / 4 + 255) / 256, 256, 0, stream>>>(colidx, dinv, dinvE);

  const int NAB = (N_NODES + 31) / 32;  // 1563
  k_agg_gemm<<<NAB, 256, 0, stream>>>(A_bf, rowptr, colidx, dinv, dinvE, b1, Wt2g, B_bf);
  k_agg_fin<<<NAB, 256, 0, stream>>>(B_bf, rowptr, colidx, dinv, b2, Wc, bc, out);
}